// Round 18
// baseline (360.796 us; speedup 1.0000x reference)
//
#include <hip/hip_runtime.h>
#include <hip/hip_bf16.h>

#define NN 8192
#define INF_ 512
#define OUTF 256

typedef __attribute__((ext_vector_type(8))) short short8;
typedef __attribute__((ext_vector_type(16))) float f32x16;

static __device__ __forceinline__ short f2bf(float x) {
  unsigned u = __float_as_uint(x);
  unsigned r = (u + 0x7fff + ((u >> 16) & 1)) >> 16;   // RNE to bf16
  return (short)r;
}
static __device__ __forceinline__ float bf2f(short s) {
  return __uint_as_float(((unsigned)(unsigned short)s) << 16);
}
// async global->LDS, 16B per lane; LDS dest = wave-uniform base + lane*16
static __device__ __forceinline__ void gl2lds16(const short* g, short* l) {
  __builtin_amdgcn_global_load_lds(
      (const __attribute__((address_space(1))) unsigned int*)g,
      (__attribute__((address_space(3))) unsigned int*)l, 16, 0, 0);
}

// ---------------- Kernel 0: WT_hi/lo[col][k] = split-bf16(W[k][col]) -------
__global__ __launch_bounds__(256) void k_prepW(const float* __restrict__ W,
                                               short* __restrict__ WThi,
                                               short* __restrict__ WTlo) {
  __shared__ float tile[64][65];
  const int t = threadIdx.x;
  const int r0 = blockIdx.x * 64;   // k dim
  const int c0 = blockIdx.y * 64;   // col dim
  {
    const int ri = t >> 2, cq = t & 3;
    const float4* src = (const float4*)(W + (size_t)(r0 + ri) * OUTF + c0 + cq * 16);
#pragma unroll
    for (int q = 0; q < 4; ++q) {
      float4 v = src[q];
      int c = cq * 16 + q * 4;
      tile[ri][c + 0] = v.x; tile[ri][c + 1] = v.y;
      tile[ri][c + 2] = v.z; tile[ri][c + 3] = v.w;
    }
  }
  __syncthreads();
  {
    const int cj = t >> 2, rq = t & 3;
    alignas(16) short hi[16], lo[16];
#pragma unroll
    for (int q = 0; q < 16; ++q) {
      float x = tile[rq * 16 + q][cj];
      short hb = f2bf(x);
      hi[q] = hb;
      lo[q] = f2bf(x - bf2f(hb));
    }
    short* dh = WThi + (size_t)(c0 + cj) * INF_ + r0 + rq * 16;
    short* dl = WTlo + (size_t)(c0 + cj) * INF_ + r0 + rq * 16;
    *(float4*)dh = *(float4*)&hi[0];
    *(float4*)(dh + 8) = *(float4*)&hi[8];
    *(float4*)dl = *(float4*)&lo[0];
    *(float4*)(dl + 8) = *(float4*)&lo[8];
  }
}

// ---------------- Kernel 1: Wh = h @ W via split-bf16 MFMA -----------------
// (validated: 64x64 tile, grid (128,4) = 2 blocks/CU, B ping-pong)
__global__ __launch_bounds__(256, 2) void k_gemm_hW(const float* __restrict__ h,
                                                    const short* __restrict__ WThi,
                                                    const short* __restrict__ WTlo,
                                                    float* __restrict__ Wh,
                                                    short* __restrict__ WhbT) {
  __shared__ short Ahi[64 * 64];    // 8 KB, rows 128B, XOR-swizzled
  __shared__ short Alo[64 * 64];    // 8 KB
  __shared__ short Trans[64 * 72];  // 9 KB, [col][row] padded
  const int t = threadIdx.x;
  const int rb = blockIdx.x * 64;
  const int cb = blockIdx.y * 64;
  const int sr = t >> 2, sq = t & 3;        // h-stage: row, 16-k chunk
  const int lane = t & 63, wid = t >> 6;
  const int l31 = lane & 31, lhi = lane >> 5;
  const int wrow = (wid >> 1) * 32;         // 0/32
  const int wc = wid & 1;                   // 32-col half
  char* AhiB = (char*)Ahi;
  char* AloB = (char*)Alo;
  const int arow = wrow + l31;
  const int aswz = (arow & 7) << 4;
  const int sbyte = sr * 128 + sq * 32;
  const int sswz = (sr & 7) << 4;
  const size_t bcol = (size_t)(cb + wc * 32 + l31) * INF_ + lhi * 8;

  f32x16 acc = (f32x16)(0.f);

  float4 hreg[4];
  {
    const float4* hs = (const float4*)(h + (size_t)(rb + sr) * INF_ + sq * 16);
#pragma unroll
    for (int s = 0; s < 4; ++s) hreg[s] = hs[s];
  }
  short8 Bh[2][4], Bl[2][4];
#pragma unroll
  for (int k16 = 0; k16 < 4; ++k16) {
    Bh[0][k16] = *(const short8*)(WThi + bcol + k16 * 16);
    Bl[0][k16] = *(const short8*)(WTlo + bcol + k16 * 16);
  }

#pragma unroll
  for (int s8 = 0; s8 < 8; ++s8) {
    const int kb = s8 * 64;
    const int cur = s8 & 1, nxt = cur ^ 1;
    {
      alignas(16) short whi[16], wlo[16];
#pragma unroll
      for (int s = 0; s < 4; ++s) {
        float xs[4] = {hreg[s].x, hreg[s].y, hreg[s].z, hreg[s].w};
#pragma unroll
        for (int u = 0; u < 4; ++u) {
          short hb = f2bf(xs[u]);
          whi[s * 4 + u] = hb;
          wlo[s * 4 + u] = f2bf(xs[u] - bf2f(hb));
        }
      }
      *(float4*)(AhiB + (sbyte ^ sswz)) = *(float4*)&whi[0];
      *(float4*)(AhiB + ((sbyte + 16) ^ sswz)) = *(float4*)&whi[8];
      *(float4*)(AloB + (sbyte ^ sswz)) = *(float4*)&wlo[0];
      *(float4*)(AloB + ((sbyte + 16) ^ sswz)) = *(float4*)&wlo[8];
    }
    __syncthreads();
    if (s8 < 7) {
      const float4* hn = (const float4*)(h + (size_t)(rb + sr) * INF_ + kb + 64 + sq * 16);
#pragma unroll
      for (int s = 0; s < 4; ++s) hreg[s] = hn[s];
#pragma unroll
      for (int k16 = 0; k16 < 4; ++k16) {
        Bh[nxt][k16] = *(const short8*)(WThi + bcol + kb + 64 + k16 * 16);
        Bl[nxt][k16] = *(const short8*)(WTlo + bcol + kb + 64 + k16 * 16);
      }
    }
#pragma unroll
    for (int k16 = 0; k16 < 4; ++k16) {
      const int abyte = (arow * 128 + k16 * 32 + lhi * 16) ^ aswz;
      short8 ah = *(const short8*)(AhiB + abyte);
      short8 al = *(const short8*)(AloB + abyte);
      acc = __builtin_amdgcn_mfma_f32_32x32x16_bf16(ah, Bh[cur][k16], acc, 0, 0, 0);
      acc = __builtin_amdgcn_mfma_f32_32x32x16_bf16(ah, Bl[cur][k16], acc, 0, 0, 0);
      acc = __builtin_amdgcn_mfma_f32_32x32x16_bf16(al, Bh[cur][k16], acc, 0, 0, 0);
    }
    __syncthreads();
  }
#pragma unroll
  for (int q = 0; q < 16; ++q) {
    const int row = wrow + 4 * lhi + (q & 3) + 8 * (q >> 2);   // 0..63
    const int col = wc * 32 + l31;                             // 0..63
    Wh[(size_t)(rb + row) * OUTF + cb + col] = acc[q];
    Trans[col * 72 + row] = f2bf(acc[q]);
  }
  __syncthreads();
  {
    const int cj = t >> 2, rq = t & 3;   // col 0..63, row-quarter
    alignas(16) short tmp[16];
#pragma unroll
    for (int q = 0; q < 16; ++q) tmp[q] = Trans[cj * 72 + rq * 16 + q];
    short* dst = WhbT + (size_t)(cb + cj) * NN + rb + rq * 16;
    *(float4*)dst = *(float4*)&tmp[0];
    *(float4*)(dst + 8) = *(float4*)&tmp[8];
  }
}

// ---------------- Kernel 2: s/d per-row attention scalars ------------------
__global__ __launch_bounds__(256) void k_attn_sd(const float* __restrict__ Wh,
                                                 const float* __restrict__ a_src,
                                                 const float* __restrict__ a_dst,
                                                 float* __restrict__ sv,
                                                 float* __restrict__ dvv) {
  const int lane = threadIdx.x & 63;
  const int wave = threadIdx.x >> 6;
  const int row = blockIdx.x * 4 + wave;
  float4 wv = *reinterpret_cast<const float4*>(&Wh[(size_t)row * OUTF + lane * 4]);
  float4 as = *reinterpret_cast<const float4*>(&a_src[lane * 4]);
  float4 ad = *reinterpret_cast<const float4*>(&a_dst[lane * 4]);
  float ps = wv.x * as.x + wv.y * as.y + wv.z * as.z + wv.w * as.w;
  float pd = wv.x * ad.x + wv.y * ad.y + wv.z * ad.z + wv.w * ad.w;
#pragma unroll
  for (int off2 = 32; off2 > 0; off2 >>= 1) {
    ps += __shfl_down(ps, off2);
    pd += __shfl_down(pd, off2);
  }
  if (lane == 0) {
    sv[row] = ps;
    dvv[row] = pd;
  }
}

// ---------------- Kernel 3: fused mask+softmax(unnorm)+PV via MFMA ---------
// Round-15 structure (coalesced PGEN + Pl, plain __syncthreads, gl2lds V)
// with 128-row tiles / 512 thr / 8 waves: V-staging bytes and barriers per
// output row HALVE, occupancy -> 16 waves/CU (2 blocks x 8 waves; LDS 80KB).
// Wave w = 32 rows x 128 cols (wrow=(w&3)*32, wcol=(w>>2)*128). dv loaded
// in-PGEN (L2-hot 32KB) to keep VGPR <= 128 at launch_bounds(512,4).
__global__ __launch_bounds__(512, 4) void k_attn_pv(const int* __restrict__ adj,
                                                    const short* __restrict__ WhbT,
                                                    const float* __restrict__ sv,
                                                    const float* __restrict__ dv,
                                                    float* __restrict__ accP,
                                                    float* __restrict__ zP,
                                                    int jspan) {
  __shared__ short Vt0[256 * 64];  // 32 KB, [col][k] rows 128B, XOR-swizzled
  __shared__ short Vt1[256 * 64];  // 32 KB
  __shared__ short Pl[128 * 64];   // 16 KB, [row][k] rows 128B, XOR-swizzled
  const int t = threadIdx.x;       // 0..511
  const int rb = blockIdx.x * 128;
  const int pr = t >> 2;           // P-gen row 0..127
  const int pq = t & 3;            // P-gen 16-wide j-chunk
  const float s_i = sv[rb + pr];
  const int lane = t & 63;
  const int wid = t >> 6;          // 0..7
  const int l31 = lane & 31;
  const int lhi = lane >> 5;
  const int wrow = (wid & 3) * 32;   // 0/32/64/96
  const int wcol = (wid >> 2) * 128; // 0/128
  char* PlB = (char*)Pl;
  const int arow = wrow + l31;
  const int abase = arow * 128 + lhi * 16;
  const int aswz = (arow & 7) << 4;
  const int pbyte = pr * 128 + pq * 32;
  const int pswz = (pr & 7) << 4;
  // V staging: wave w stages cols w*32..+32 (4 instrs x 1KB); instr r covers
  // cols w*32+r*8..+8; lane l -> col +(l>>3), phys slot l&7; source chunk
  // pre-swizzled (l&7)^((l>>3)&7) (c&7 == (l>>3)&7 since r*8 = 0 mod 8).
  const int vcol0 = wid * 32 + (lane >> 3);
  const int vchunk = ((lane & 7) ^ ((lane >> 3) & 7)) * 8;
  const short* vsrc0 = WhbT + (size_t)vcol0 * NN + vchunk;
  short* vdst0 = Vt0 + wid * 2048;   // 32 cols x 128B = 4KB = 2048 shorts
  short* vdst1 = Vt1 + wid * 2048;

  f32x16 acc[4];
#pragma unroll
  for (int ct = 0; ct < 4; ++ct) acc[ct] = (f32x16)(0.f);
  float zacc = 0.f;

  const int j0 = blockIdx.y * jspan;
  const int iters = jspan >> 6;    // 16 at S=8; even, >= 4

#define ISSUE_V(JB, VDST)                                                     \
  _Pragma("unroll")                                                           \
  for (int r = 0; r < 4; ++r)                                                 \
    gl2lds16(vsrc0 + (JB) + r * 8 * NN, (VDST) + r * 512);

#define LOAD_A(JB, AR)                                                        \
  {                                                                           \
    const int4* ap = (const int4*)(adj + (size_t)(rb + pr) * NN + (JB) + pq * 16); \
    _Pragma("unroll") for (int q = 0; q < 4; ++q) AR[q] = ap[q];              \
  }

#define PGEN_STORE(AR, JB)                                                    \
  {                                                                           \
    const float4* dp = (const float4*)(dv + (JB) + pq * 16);                  \
    alignas(16) short wb[16];                                                 \
    _Pragma("unroll")                                                         \
    for (int q = 0; q < 4; ++q) {                                             \
      float4 dq = dp[q];                                                      \
      float ev[4] = {dq.x, dq.y, dq.z, dq.w};                                 \
      int av[4] = {AR[q].x, AR[q].y, AR[q].z, AR[q].w};                       \
      _Pragma("unroll")                                                       \
      for (int u = 0; u < 4; ++u) {                                           \
        float e = s_i + ev[u];                                                \
        e = e >= 0.f ? e : 0.2f * e;                                          \
        float w = av[u] > 0 ? __expf(e) : 0.f;                                \
        short b = f2bf(w);                                                    \
        wb[q * 4 + u] = b;                                                    \
        zacc += bf2f(b);                                                      \
      }                                                                       \
    }                                                                         \
    *(float4*)(PlB + (pbyte ^ pswz)) = *(float4*)&wb[0];                      \
    *(float4*)(PlB + ((pbyte + 16) ^ pswz)) = *(float4*)&wb[8];               \
  }

#define MFMA_PHASE(VTB)                                                       \
  _Pragma("unroll")                                                           \
  for (int ks = 0; ks < 4; ++ks) {                                            \
    short8 af = *(const short8*)(PlB + ((abase + ks * 32) ^ aswz));           \
    _Pragma("unroll")                                                         \
    for (int ct = 0; ct < 4; ++ct) {                                          \
      const int c = wcol + ct * 32 + l31;                                     \
      short8 bf = *(const short8*)((char*)(VTB) +                             \
                    ((c * 128 + ks * 32 + lhi * 16) ^ ((c & 7) << 4)));       \
      acc[ct] = __builtin_amdgcn_mfma_f32_32x32x16_bf16(af, bf, acc[ct], 0, 0, 0); \
    }                                                                         \
  }

  // ---- prologue: adj for tiles 0,1 -> regs; V(0) -> Vt0 ----
  int4 aA[4], aB[4];
  LOAD_A(j0, aA);
  LOAD_A(j0 + 64, aB);
  ISSUE_V(j0, vdst0);

  for (int it = 0; it < iters; it += 2) {
    const int jb = j0 + it * 64;
    // ---- even sub-iter: consume A + Vt0 ----
    PGEN_STORE(aA, jb);
    __syncthreads();                       // V(it) landed
    ISSUE_V(jb + 64, vdst1);               // V(it+1), flies across MFMA
    if (it + 2 < iters) LOAD_A(jb + 128, aA);        // adj(it+2), 2-deep
    MFMA_PHASE(Vt0);
    __syncthreads();
    // ---- odd sub-iter: consume B + Vt1 ----
    PGEN_STORE(aB, jb + 64);
    __syncthreads();
    if (it + 2 < iters) ISSUE_V(jb + 128, vdst0);    // V(it+2)
    if (it + 3 < iters) LOAD_A(jb + 192, aB);        // adj(it+3)
    MFMA_PHASE(Vt1);
    __syncthreads();
  }
#undef ISSUE_V
#undef LOAD_A
#undef PGEN_STORE
#undef MFMA_PHASE

  // ---- z: reduce 4 lanes (same row) via shfl ----
  float z2 = zacc + __shfl_xor(zacc, 1, 64);
  z2 += __shfl_xor(z2, 2, 64);
  if (pq == 0) zP[blockIdx.y * NN + rb + pr] = z2;
  // ---- acc epilogue ----
  const size_t slab = (size_t)blockIdx.y * NN * OUTF;
#pragma unroll
  for (int ct = 0; ct < 4; ++ct) {
#pragma unroll
    for (int q = 0; q < 16; ++q) {
      const int row = rb + wrow + 4 * lhi + (q & 3) + 8 * (q >> 2);
      const int col = wcol + ct * 32 + l31;
      accP[slab + (size_t)row * OUTF + col] = acc[ct][q];
    }
  }
}

// ---------------- Kernel 4: combine partials, normalize --------------------
__global__ __launch_bounds__(256) void k_reduce(const float* __restrict__ accP,
                                                const float* __restrict__ zP,
                                                float* __restrict__ out, int S) {
  const int row = blockIdx.x;
  const int f = threadIdx.x;
  const size_t idx = (size_t)row * OUTF + f;
  float a = 0.f, z = 0.f;
  for (int s = 0; s < S; ++s) {
    a += accP[(size_t)s * NN * OUTF + idx];
    z += zP[s * NN + row];
  }
  out[idx] = a / z;
}

extern "C" void kernel_launch(void* const* d_in, const int* in_sizes, int n_in,
                              void* d_out, int out_size, void* d_ws, size_t ws_size,
                              hipStream_t stream) {
  const float* h = (const float*)d_in[0];
  const int* adj = (const int*)d_in[1];
  const float* W = (const float*)d_in[2];
  const float* a_src = (const float*)d_in[3];
  const float* a_dst = (const float*)d_in[4];
  float* out = (float*)d_out;

  char* ws = (char*)d_ws;
  float* Wh = (float*)ws;                                    // 8 MB
  short* WhbT = (short*)(ws + (size_t)NN * OUTF * 4);        // 4 MB
  float* sv = (float*)(ws + (size_t)NN * OUTF * 6);          // 32 KB
  float* dvv = sv + NN;                                      // 32 KB
  float* zP = dvv + NN;                                      // 8*32 KB
  short* WThi = (short*)(zP + 8 * NN);                       // 256 KB
  short* WTlo = WThi + (size_t)OUTF * INF_;                  // 256 KB
  size_t off = (size_t)NN * OUTF * 6 + 2 * (size_t)NN * 4 + 8 * (size_t)NN * 4
             + 2 * (size_t)OUTF * INF_ * 2;
  off = (off + 255) & ~(size_t)255;
  const size_t slab_bytes = (size_t)NN * OUTF * 4;
  int S;
  float* accP;
  if (ws_size >= off + 8 * slab_bytes) { S = 8; accP = (float*)(ws + off); }      // grid (64,8)=512 blocks, 2/CU
  else if (ws_size >= off + 4 * slab_bytes) { S = 4; accP = (float*)(ws + off); }
  else if (ws_size >= off + 2 * slab_bytes) { S = 2; accP = (float*)(ws + off); }
  else { S = 2; accP = out; S = 1; accP = (float*)(ws + off); }  // minimal fallback

  k_prepW<<<dim3(INF_ / 64, OUTF / 64), dim3(256), 0, stream>>>(W, WThi, WTlo);
  k_gemm_hW<<<dim3(NN / 64, OUTF / 64), dim3(256), 0, stream>>>(h, WThi, WTlo, Wh, WhbT);
  k_attn_sd<<<dim3(NN / 4), dim3(256), 0, stream>>>(Wh, a_src, a_dst, sv, dvv);
  k_attn_pv<<<dim3(NN / 128, S), dim3(512), 0, stream>>>(adj, WhbT, sv, dvv, accP, zP, NN / S);
  k_reduce<<<dim3(NN), dim3(256), 0, stream>>>(accP, zP, out, S);
}

// Round 19
// 186.131 us; speedup vs baseline: 1.9384x; 1.9384x over previous
//
#include <hip/hip_runtime.h>
#include <hip/hip_bf16.h>

#define NN 8192
#define INF_ 512
#define OUTF 256

typedef __attribute__((ext_vector_type(8))) short short8;
typedef __attribute__((ext_vector_type(16))) float f32x16;

static __device__ __forceinline__ short f2bf(float x) {
  unsigned u = __float_as_uint(x);
  unsigned r = (u + 0x7fff + ((u >> 16) & 1)) >> 16;   // RNE to bf16
  return (short)r;
}
static __device__ __forceinline__ float bf2f(short s) {
  return __uint_as_float(((unsigned)(unsigned short)s) << 16);
}
// async global->LDS, 16B per lane; LDS dest = wave-uniform base + lane*16
static __device__ __forceinline__ void gl2lds16(const short* g, short* l) {
  __builtin_amdgcn_global_load_lds(
      (const __attribute__((address_space(1))) unsigned int*)g,
      (__attribute__((address_space(3))) unsigned int*)l, 16, 0, 0);
}

// ---------------- Kernel 0: WT_hi/lo[col][k] = split-bf16(W[k][col]) -------
__global__ __launch_bounds__(256) void k_prepW(const float* __restrict__ W,
                                               short* __restrict__ WThi,
                                               short* __restrict__ WTlo) {
  __shared__ float tile[64][65];
  const int t = threadIdx.x;
  const int r0 = blockIdx.x * 64;   // k dim
  const int c0 = blockIdx.y * 64;   // col dim
  {
    const int ri = t >> 2, cq = t & 3;
    const float4* src = (const float4*)(W + (size_t)(r0 + ri) * OUTF + c0 + cq * 16);
#pragma unroll
    for (int q = 0; q < 4; ++q) {
      float4 v = src[q];
      int c = cq * 16 + q * 4;
      tile[ri][c + 0] = v.x; tile[ri][c + 1] = v.y;
      tile[ri][c + 2] = v.z; tile[ri][c + 3] = v.w;
    }
  }
  __syncthreads();
  {
    const int cj = t >> 2, rq = t & 3;
    alignas(16) short hi[16], lo[16];
#pragma unroll
    for (int q = 0; q < 16; ++q) {
      float x = tile[rq * 16 + q][cj];
      short hb = f2bf(x);
      hi[q] = hb;
      lo[q] = f2bf(x - bf2f(hb));
    }
    short* dh = WThi + (size_t)(c0 + cj) * INF_ + r0 + rq * 16;
    short* dl = WTlo + (size_t)(c0 + cj) * INF_ + r0 + rq * 16;
    *(float4*)dh = *(float4*)&hi[0];
    *(float4*)(dh + 8) = *(float4*)&hi[8];
    *(float4*)dl = *(float4*)&lo[0];
    *(float4*)(dl + 8) = *(float4*)&lo[8];
  }
}

// ---------------- Kernel 1: Wh = h @ W via split-bf16 MFMA -----------------
// (validated: 64x64 tile, grid (128,4) = 2 blocks/CU, B ping-pong)
__global__ __launch_bounds__(256, 2) void k_gemm_hW(const float* __restrict__ h,
                                                    const short* __restrict__ WThi,
                                                    const short* __restrict__ WTlo,
                                                    float* __restrict__ Wh,
                                                    short* __restrict__ WhbT) {
  __shared__ short Ahi[64 * 64];    // 8 KB, rows 128B, XOR-swizzled
  __shared__ short Alo[64 * 64];    // 8 KB
  __shared__ short Trans[64 * 72];  // 9 KB, [col][row] padded
  const int t = threadIdx.x;
  const int rb = blockIdx.x * 64;
  const int cb = blockIdx.y * 64;
  const int sr = t >> 2, sq = t & 3;        // h-stage: row, 16-k chunk
  const int lane = t & 63, wid = t >> 6;
  const int l31 = lane & 31, lhi = lane >> 5;
  const int wrow = (wid >> 1) * 32;         // 0/32
  const int wc = wid & 1;                   // 32-col half
  char* AhiB = (char*)Ahi;
  char* AloB = (char*)Alo;
  const int arow = wrow + l31;
  const int aswz = (arow & 7) << 4;
  const int sbyte = sr * 128 + sq * 32;
  const int sswz = (sr & 7) << 4;
  const size_t bcol = (size_t)(cb + wc * 32 + l31) * INF_ + lhi * 8;

  f32x16 acc = (f32x16)(0.f);

  float4 hreg[4];
  {
    const float4* hs = (const float4*)(h + (size_t)(rb + sr) * INF_ + sq * 16);
#pragma unroll
    for (int s = 0; s < 4; ++s) hreg[s] = hs[s];
  }
  short8 Bh[2][4], Bl[2][4];
#pragma unroll
  for (int k16 = 0; k16 < 4; ++k16) {
    Bh[0][k16] = *(const short8*)(WThi + bcol + k16 * 16);
    Bl[0][k16] = *(const short8*)(WTlo + bcol + k16 * 16);
  }

#pragma unroll
  for (int s8 = 0; s8 < 8; ++s8) {
    const int kb = s8 * 64;
    const int cur = s8 & 1, nxt = cur ^ 1;
    {
      alignas(16) short whi[16], wlo[16];
#pragma unroll
      for (int s = 0; s < 4; ++s) {
        float xs[4] = {hreg[s].x, hreg[s].y, hreg[s].z, hreg[s].w};
#pragma unroll
        for (int u = 0; u < 4; ++u) {
          short hb = f2bf(xs[u]);
          whi[s * 4 + u] = hb;
          wlo[s * 4 + u] = f2bf(xs[u] - bf2f(hb));
        }
      }
      *(float4*)(AhiB + (sbyte ^ sswz)) = *(float4*)&whi[0];
      *(float4*)(AhiB + ((sbyte + 16) ^ sswz)) = *(float4*)&whi[8];
      *(float4*)(AloB + (sbyte ^ sswz)) = *(float4*)&wlo[0];
      *(float4*)(AloB + ((sbyte + 16) ^ sswz)) = *(float4*)&wlo[8];
    }
    __syncthreads();
    if (s8 < 7) {
      const float4* hn = (const float4*)(h + (size_t)(rb + sr) * INF_ + kb + 64 + sq * 16);
#pragma unroll
      for (int s = 0; s < 4; ++s) hreg[s] = hn[s];
#pragma unroll
      for (int k16 = 0; k16 < 4; ++k16) {
        Bh[nxt][k16] = *(const short8*)(WThi + bcol + kb + 64 + k16 * 16);
        Bl[nxt][k16] = *(const short8*)(WTlo + bcol + kb + 64 + k16 * 16);
      }
    }
#pragma unroll
    for (int k16 = 0; k16 < 4; ++k16) {
      const int abyte = (arow * 128 + k16 * 32 + lhi * 16) ^ aswz;
      short8 ah = *(const short8*)(AhiB + abyte);
      short8 al = *(const short8*)(AloB + abyte);
      acc = __builtin_amdgcn_mfma_f32_32x32x16_bf16(ah, Bh[cur][k16], acc, 0, 0, 0);
      acc = __builtin_amdgcn_mfma_f32_32x32x16_bf16(ah, Bl[cur][k16], acc, 0, 0, 0);
      acc = __builtin_amdgcn_mfma_f32_32x32x16_bf16(al, Bh[cur][k16], acc, 0, 0, 0);
    }
    __syncthreads();
  }
#pragma unroll
  for (int q = 0; q < 16; ++q) {
    const int row = wrow + 4 * lhi + (q & 3) + 8 * (q >> 2);   // 0..63
    const int col = wc * 32 + l31;                             // 0..63
    Wh[(size_t)(rb + row) * OUTF + cb + col] = acc[q];
    Trans[col * 72 + row] = f2bf(acc[q]);
  }
  __syncthreads();
  {
    const int cj = t >> 2, rq = t & 3;   // col 0..63, row-quarter
    alignas(16) short tmp[16];
#pragma unroll
    for (int q = 0; q < 16; ++q) tmp[q] = Trans[cj * 72 + rq * 16 + q];
    short* dst = WhbT + (size_t)(cb + cj) * NN + rb + rq * 16;
    *(float4*)dst = *(float4*)&tmp[0];
    *(float4*)(dst + 8) = *(float4*)&tmp[8];
  }
}

// ---------------- Kernel 2: s/d per-row attention scalars ------------------
__global__ __launch_bounds__(256) void k_attn_sd(const float* __restrict__ Wh,
                                                 const float* __restrict__ a_src,
                                                 const float* __restrict__ a_dst,
                                                 float* __restrict__ sv,
                                                 float* __restrict__ dvv) {
  const int lane = threadIdx.x & 63;
  const int wave = threadIdx.x >> 6;
  const int row = blockIdx.x * 4 + wave;
  float4 wv = *reinterpret_cast<const float4*>(&Wh[(size_t)row * OUTF + lane * 4]);
  float4 as = *reinterpret_cast<const float4*>(&a_src[lane * 4]);
  float4 ad = *reinterpret_cast<const float4*>(&a_dst[lane * 4]);
  float ps = wv.x * as.x + wv.y * as.y + wv.z * as.z + wv.w * as.w;
  float pd = wv.x * ad.x + wv.y * ad.y + wv.z * ad.z + wv.w * ad.w;
#pragma unroll
  for (int off2 = 32; off2 > 0; off2 >>= 1) {
    ps += __shfl_down(ps, off2);
    pd += __shfl_down(pd, off2);
  }
  if (lane == 0) {
    sv[row] = ps;
    dvv[row] = pd;
  }
}

// ---------------- Kernel 3: fused mask+softmax(unnorm)+PV via MFMA ---------
// Round-18 geometry (128 rows x 256 cols, 512 thr / 8 waves, halved V-traffic
// and barriers per row) with the launch-bounds bug FIXED: (512,2) -> 128-VGPR
// cap (usage ~116: acc 64 + adj 32 + misc). Round 18's (512,4) forced a
// 64-VGPR cap -> acc spilled to scratch (WRITE_SIZE 320MB, PV 343us).
__global__ __launch_bounds__(512, 2) void k_attn_pv(const int* __restrict__ adj,
                                                    const short* __restrict__ WhbT,
                                                    const float* __restrict__ sv,
                                                    const float* __restrict__ dv,
                                                    float* __restrict__ accP,
                                                    float* __restrict__ zP,
                                                    int jspan) {
  __shared__ short Vt0[256 * 64];  // 32 KB, [col][k] rows 128B, XOR-swizzled
  __shared__ short Vt1[256 * 64];  // 32 KB
  __shared__ short Pl[128 * 64];   // 16 KB, [row][k] rows 128B, XOR-swizzled
  const int t = threadIdx.x;       // 0..511
  const int rb = blockIdx.x * 128;
  const int pr = t >> 2;           // P-gen row 0..127
  const int pq = t & 3;            // P-gen 16-wide j-chunk
  const float s_i = sv[rb + pr];
  const int lane = t & 63;
  const int wid = t >> 6;          // 0..7
  const int l31 = lane & 31;
  const int lhi = lane >> 5;
  const int wrow = (wid & 3) * 32;   // 0/32/64/96
  const int wcol = (wid >> 2) * 128; // 0/128
  char* PlB = (char*)Pl;
  const int arow = wrow + l31;
  const int abase = arow * 128 + lhi * 16;
  const int aswz = (arow & 7) << 4;
  const int pbyte = pr * 128 + pq * 32;
  const int pswz = (pr & 7) << 4;
  // V staging: wave w stages cols w*32..+32 (4 instrs x 1KB); instr r covers
  // cols w*32+r*8..+8; lane l -> col +(l>>3), phys slot l&7; source chunk
  // pre-swizzled (l&7)^((l>>3)&7).
  const int vcol0 = wid * 32 + (lane >> 3);
  const int vchunk = ((lane & 7) ^ ((lane >> 3) & 7)) * 8;
  const short* vsrc0 = WhbT + (size_t)vcol0 * NN + vchunk;
  short* vdst0 = Vt0 + wid * 2048;   // 32 cols x 128B = 4KB = 2048 shorts
  short* vdst1 = Vt1 + wid * 2048;

  f32x16 acc[4];
#pragma unroll
  for (int ct = 0; ct < 4; ++ct) acc[ct] = (f32x16)(0.f);
  float zacc = 0.f;

  const int j0 = blockIdx.y * jspan;
  const int iters = jspan >> 6;    // 16 at S=8; even, >= 4

#define ISSUE_V(JB, VDST)                                                     \
  _Pragma("unroll")                                                           \
  for (int r = 0; r < 4; ++r)                                                 \
    gl2lds16(vsrc0 + (JB) + r * 8 * NN, (VDST) + r * 512);

#define LOAD_A(JB, AR)                                                        \
  {                                                                           \
    const int4* ap = (const int4*)(adj + (size_t)(rb + pr) * NN + (JB) + pq * 16); \
    _Pragma("unroll") for (int q = 0; q < 4; ++q) AR[q] = ap[q];              \
  }

#define PGEN_STORE(AR, JB)                                                    \
  {                                                                           \
    const float4* dp = (const float4*)(dv + (JB) + pq * 16);                  \
    alignas(16) short wb[16];                                                 \
    _Pragma("unroll")                                                         \
    for (int q = 0; q < 4; ++q) {                                             \
      float4 dq = dp[q];                                                      \
      float ev[4] = {dq.x, dq.y, dq.z, dq.w};                                 \
      int av[4] = {AR[q].x, AR[q].y, AR[q].z, AR[q].w};                       \
      _Pragma("unroll")                                                       \
      for (int u = 0; u < 4; ++u) {                                           \
        float e = s_i + ev[u];                                                \
        e = e >= 0.f ? e : 0.2f * e;                                          \
        float w = av[u] > 0 ? __expf(e) : 0.f;                                \
        short b = f2bf(w);                                                    \
        wb[q * 4 + u] = b;                                                    \
        zacc += bf2f(b);                                                      \
      }                                                                       \
    }                                                                         \
    *(float4*)(PlB + (pbyte ^ pswz)) = *(float4*)&wb[0];                      \
    *(float4*)(PlB + ((pbyte + 16) ^ pswz)) = *(float4*)&wb[8];               \
  }

#define MFMA_PHASE(VTB)                                                       \
  _Pragma("unroll")                                                           \
  for (int ks = 0; ks < 4; ++ks) {                                            \
    short8 af = *(const short8*)(PlB + ((abase + ks * 32) ^ aswz));           \
    _Pragma("unroll")                                                         \
    for (int ct = 0; ct < 4; ++ct) {                                          \
      const int c = wcol + ct * 32 + l31;                                     \
      short8 bf = *(const short8*)((char*)(VTB) +                             \
                    ((c * 128 + ks * 32 + lhi * 16) ^ ((c & 7) << 4)));       \
      acc[ct] = __builtin_amdgcn_mfma_f32_32x32x16_bf16(af, bf, acc[ct], 0, 0, 0); \
    }                                                                         \
  }

  // ---- prologue: adj for tiles 0,1 -> regs; V(0) -> Vt0 ----
  int4 aA[4], aB[4];
  LOAD_A(j0, aA);
  LOAD_A(j0 + 64, aB);
  ISSUE_V(j0, vdst0);

  for (int it = 0; it < iters; it += 2) {
    const int jb = j0 + it * 64;
    // ---- even sub-iter: consume A + Vt0 ----
    PGEN_STORE(aA, jb);
    __syncthreads();                       // V(it) landed
    ISSUE_V(jb + 64, vdst1);               // V(it+1), flies across MFMA
    if (it + 2 < iters) LOAD_A(jb + 128, aA);        // adj(it+2), 2-deep
    MFMA_PHASE(Vt0);
    __syncthreads();
    // ---- odd sub-iter: consume B + Vt1 ----
    PGEN_STORE(aB, jb + 64);
    __syncthreads();
    if (it + 2 < iters) ISSUE_V(jb + 128, vdst0);    // V(it+2)
    if (it + 3 < iters) LOAD_A(jb + 192, aB);        // adj(it+3)
    MFMA_PHASE(Vt1);
    __syncthreads();
  }
#undef ISSUE_V
#undef LOAD_A
#undef PGEN_STORE
#undef MFMA_PHASE

  // ---- z: reduce 4 lanes (same row) via shfl ----
  float z2 = zacc + __shfl_xor(zacc, 1, 64);
  z2 += __shfl_xor(z2, 2, 64);
  if (pq == 0) zP[blockIdx.y * NN + rb + pr] = z2;
  // ---- acc epilogue ----
  const size_t slab = (size_t)blockIdx.y * NN * OUTF;
#pragma unroll
  for (int ct = 0; ct < 4; ++ct) {
#pragma unroll
    for (int q = 0; q < 16; ++q) {
      const int row = rb + wrow + 4 * lhi + (q & 3) + 8 * (q >> 2);
      const int col = wcol + ct * 32 + l31;
      accP[slab + (size_t)row * OUTF + col] = acc[ct][q];
    }
  }
}

// ---------------- Kernel 4: combine partials, normalize --------------------
__global__ __launch_bounds__(256) void k_reduce(const float* __restrict__ accP,
                                                const float* __restrict__ zP,
                                                float* __restrict__ out, int S) {
  const int row = blockIdx.x;
  const int f = threadIdx.x;
  const size_t idx = (size_t)row * OUTF + f;
  float a = 0.f, z = 0.f;
  for (int s = 0; s < S; ++s) {
    a += accP[(size_t)s * NN * OUTF + idx];
    z += zP[s * NN + row];
  }
  out[idx] = a / z;
}

extern "C" void kernel_launch(void* const* d_in, const int* in_sizes, int n_in,
                              void* d_out, int out_size, void* d_ws, size_t ws_size,
                              hipStream_t stream) {
  const float* h = (const float*)d_in[0];
  const int* adj = (const int*)d_in[1];
  const float* W = (const float*)d_in[2];
  const float* a_src = (const float*)d_in[3];
  const float* a_dst = (const float*)d_in[4];
  float* out = (float*)d_out;

  char* ws = (char*)d_ws;
  float* Wh = (float*)ws;                                    // 8 MB
  short* WhbT = (short*)(ws + (size_t)NN * OUTF * 4);        // 4 MB
  float* sv = (float*)(ws + (size_t)NN * OUTF * 6);          // 32 KB
  float* dvv = sv + NN;                                      // 32 KB
  float* zP = dvv + NN;                                      // 8*32 KB
  short* WThi = (short*)(zP + 8 * NN);                       // 256 KB
  short* WTlo = WThi + (size_t)OUTF * INF_;                  // 256 KB
  size_t off = (size_t)NN * OUTF * 6 + 2 * (size_t)NN * 4 + 8 * (size_t)NN * 4
             + 2 * (size_t)OUTF * INF_ * 2;
  off = (off + 255) & ~(size_t)255;
  const size_t slab_bytes = (size_t)NN * OUTF * 4;
  int S;
  float* accP;
  if (ws_size >= off + 8 * slab_bytes) { S = 8; accP = (float*)(ws + off); }      // grid (64,8)=512 blocks, 2/CU
  else if (ws_size >= off + 4 * slab_bytes) { S = 4; accP = (float*)(ws + off); }
  else if (ws_size >= off + 2 * slab_bytes) { S = 2; accP = (float*)(ws + off); }
  else if (ws_size >= off + 1 * slab_bytes) { S = 1; accP = (float*)(ws + off); }
  else { S = 1; accP = out; }   // fallback: accumulate into out, normalize in place

  k_prepW<<<dim3(INF_ / 64, OUTF / 64), dim3(256), 0, stream>>>(W, WThi, WTlo);
  k_gemm_hW<<<dim3(NN / 64, OUTF / 64), dim3(256), 0, stream>>>(h, WThi, WTlo, Wh, WhbT);
  k_attn_sd<<<dim3(NN / 4), dim3(256), 0, stream>>>(Wh, a_src, a_dst, sv, dvv);
  k_attn_pv<<<dim3(NN / 128, S), dim3(512), 0, stream>>>(adj, WhbT, sv, dvv, accP, zP, NN / S);
  k_reduce<<<dim3(NN), dim3(256), 0, stream>>>(accP, zP, out, S);
}

// Round 20
// 168.750 us; speedup vs baseline: 2.1381x; 1.1030x over previous
//
#include <hip/hip_runtime.h>
#include <hip/hip_bf16.h>

#define NN 8192
#define INF_ 512
#define OUTF 256

typedef __attribute__((ext_vector_type(8))) short short8;
typedef __attribute__((ext_vector_type(16))) float f32x16;

static __device__ __forceinline__ short f2bf(float x) {
  unsigned u = __float_as_uint(x);
  unsigned r = (u + 0x7fff + ((u >> 16) & 1)) >> 16;   // RNE to bf16
  return (short)r;
}
static __device__ __forceinline__ float bf2f(short s) {
  return __uint_as_float(((unsigned)(unsigned short)s) << 16);
}
// async global->LDS, 16B per lane; LDS dest = wave-uniform base + lane*16
static __device__ __forceinline__ void gl2lds16(const short* g, short* l) {
  __builtin_amdgcn_global_load_lds(
      (const __attribute__((address_space(1))) unsigned int*)g,
      (__attribute__((address_space(3))) unsigned int*)l, 16, 0, 0);
}

// ---------------- Kernel 0: WT_hi/lo[col][k] = split-bf16(W[k][col]) -------
__global__ __launch_bounds__(256) void k_prepW(const float* __restrict__ W,
                                               short* __restrict__ WThi,
                                               short* __restrict__ WTlo) {
  __shared__ float tile[64][65];
  const int t = threadIdx.x;
  const int r0 = blockIdx.x * 64;   // k dim
  const int c0 = blockIdx.y * 64;   // col dim
  {
    const int ri = t >> 2, cq = t & 3;
    const float4* src = (const float4*)(W + (size_t)(r0 + ri) * OUTF + c0 + cq * 16);
#pragma unroll
    for (int q = 0; q < 4; ++q) {
      float4 v = src[q];
      int c = cq * 16 + q * 4;
      tile[ri][c + 0] = v.x; tile[ri][c + 1] = v.y;
      tile[ri][c + 2] = v.z; tile[ri][c + 3] = v.w;
    }
  }
  __syncthreads();
  {
    const int cj = t >> 2, rq = t & 3;
    alignas(16) short hi[16], lo[16];
#pragma unroll
    for (int q = 0; q < 16; ++q) {
      float x = tile[rq * 16 + q][cj];
      short hb = f2bf(x);
      hi[q] = hb;
      lo[q] = f2bf(x - bf2f(hb));
    }
    short* dh = WThi + (size_t)(c0 + cj) * INF_ + r0 + rq * 16;
    short* dl = WTlo + (size_t)(c0 + cj) * INF_ + r0 + rq * 16;
    *(float4*)dh = *(float4*)&hi[0];
    *(float4*)(dh + 8) = *(float4*)&hi[8];
    *(float4*)dl = *(float4*)&lo[0];
    *(float4*)(dl + 8) = *(float4*)&lo[8];
  }
}

// ---------------- Kernel 1: Wh = h @ W via split-bf16 MFMA -----------------
// (validated: 64x64 tile, grid (128,4) = 2 blocks/CU, B ping-pong)
__global__ __launch_bounds__(256, 2) void k_gemm_hW(const float* __restrict__ h,
                                                    const short* __restrict__ WThi,
                                                    const short* __restrict__ WTlo,
                                                    float* __restrict__ Wh,
                                                    short* __restrict__ WhbT) {
  __shared__ short Ahi[64 * 64];    // 8 KB, rows 128B, XOR-swizzled
  __shared__ short Alo[64 * 64];    // 8 KB
  __shared__ short Trans[64 * 72];  // 9 KB, [col][row] padded
  const int t = threadIdx.x;
  const int rb = blockIdx.x * 64;
  const int cb = blockIdx.y * 64;
  const int sr = t >> 2, sq = t & 3;        // h-stage: row, 16-k chunk
  const int lane = t & 63, wid = t >> 6;
  const int l31 = lane & 31, lhi = lane >> 5;
  const int wrow = (wid >> 1) * 32;         // 0/32
  const int wc = wid & 1;                   // 32-col half
  char* AhiB = (char*)Ahi;
  char* AloB = (char*)Alo;
  const int arow = wrow + l31;
  const int aswz = (arow & 7) << 4;
  const int sbyte = sr * 128 + sq * 32;
  const int sswz = (sr & 7) << 4;
  const size_t bcol = (size_t)(cb + wc * 32 + l31) * INF_ + lhi * 8;

  f32x16 acc = (f32x16)(0.f);

  float4 hreg[4];
  {
    const float4* hs = (const float4*)(h + (size_t)(rb + sr) * INF_ + sq * 16);
#pragma unroll
    for (int s = 0; s < 4; ++s) hreg[s] = hs[s];
  }
  short8 Bh[2][4], Bl[2][4];
#pragma unroll
  for (int k16 = 0; k16 < 4; ++k16) {
    Bh[0][k16] = *(const short8*)(WThi + bcol + k16 * 16);
    Bl[0][k16] = *(const short8*)(WTlo + bcol + k16 * 16);
  }

#pragma unroll
  for (int s8 = 0; s8 < 8; ++s8) {
    const int kb = s8 * 64;
    const int cur = s8 & 1, nxt = cur ^ 1;
    {
      alignas(16) short whi[16], wlo[16];
#pragma unroll
      for (int s = 0; s < 4; ++s) {
        float xs[4] = {hreg[s].x, hreg[s].y, hreg[s].z, hreg[s].w};
#pragma unroll
        for (int u = 0; u < 4; ++u) {
          short hb = f2bf(xs[u]);
          whi[s * 4 + u] = hb;
          wlo[s * 4 + u] = f2bf(xs[u] - bf2f(hb));
        }
      }
      *(float4*)(AhiB + (sbyte ^ sswz)) = *(float4*)&whi[0];
      *(float4*)(AhiB + ((sbyte + 16) ^ sswz)) = *(float4*)&whi[8];
      *(float4*)(AloB + (sbyte ^ sswz)) = *(float4*)&wlo[0];
      *(float4*)(AloB + ((sbyte + 16) ^ sswz)) = *(float4*)&wlo[8];
    }
    __syncthreads();
    if (s8 < 7) {
      const float4* hn = (const float4*)(h + (size_t)(rb + sr) * INF_ + kb + 64 + sq * 16);
#pragma unroll
      for (int s = 0; s < 4; ++s) hreg[s] = hn[s];
#pragma unroll
      for (int k16 = 0; k16 < 4; ++k16) {
        Bh[nxt][k16] = *(const short8*)(WThi + bcol + kb + 64 + k16 * 16);
        Bl[nxt][k16] = *(const short8*)(WTlo + bcol + kb + 64 + k16 * 16);
      }
    }
#pragma unroll
    for (int k16 = 0; k16 < 4; ++k16) {
      const int abyte = (arow * 128 + k16 * 32 + lhi * 16) ^ aswz;
      short8 ah = *(const short8*)(AhiB + abyte);
      short8 al = *(const short8*)(AloB + abyte);
      acc = __builtin_amdgcn_mfma_f32_32x32x16_bf16(ah, Bh[cur][k16], acc, 0, 0, 0);
      acc = __builtin_amdgcn_mfma_f32_32x32x16_bf16(ah, Bl[cur][k16], acc, 0, 0, 0);
      acc = __builtin_amdgcn_mfma_f32_32x32x16_bf16(al, Bh[cur][k16], acc, 0, 0, 0);
    }
    __syncthreads();
  }
#pragma unroll
  for (int q = 0; q < 16; ++q) {
    const int row = wrow + 4 * lhi + (q & 3) + 8 * (q >> 2);   // 0..63
    const int col = wc * 32 + l31;                             // 0..63
    Wh[(size_t)(rb + row) * OUTF + cb + col] = acc[q];
    Trans[col * 72 + row] = f2bf(acc[q]);
  }
  __syncthreads();
  {
    const int cj = t >> 2, rq = t & 3;   // col 0..63, row-quarter
    alignas(16) short tmp[16];
#pragma unroll
    for (int q = 0; q < 16; ++q) tmp[q] = Trans[cj * 72 + rq * 16 + q];
    short* dst = WhbT + (size_t)(cb + cj) * NN + rb + rq * 16;
    *(float4*)dst = *(float4*)&tmp[0];
    *(float4*)(dst + 8) = *(float4*)&tmp[8];
  }
}

// ---------------- Kernel 2: s/d per-row attention scalars ------------------
__global__ __launch_bounds__(256) void k_attn_sd(const float* __restrict__ Wh,
                                                 const float* __restrict__ a_src,
                                                 const float* __restrict__ a_dst,
                                                 float* __restrict__ sv,
                                                 float* __restrict__ dvv) {
  const int lane = threadIdx.x & 63;
  const int wave = threadIdx.x >> 6;
  const int row = blockIdx.x * 4 + wave;
  float4 wv = *reinterpret_cast<const float4*>(&Wh[(size_t)row * OUTF + lane * 4]);
  float4 as = *reinterpret_cast<const float4*>(&a_src[lane * 4]);
  float4 ad = *reinterpret_cast<const float4*>(&a_dst[lane * 4]);
  float ps = wv.x * as.x + wv.y * as.y + wv.z * as.z + wv.w * as.w;
  float pd = wv.x * ad.x + wv.y * ad.y + wv.z * ad.z + wv.w * ad.w;
#pragma unroll
  for (int off2 = 32; off2 > 0; off2 >>= 1) {
    ps += __shfl_down(ps, off2);
    pd += __shfl_down(pd, off2);
  }
  if (lane == 0) {
    sv[row] = ps;
    dvv[row] = pd;
  }
}

// ---------------- Kernel 3: fused mask+softmax(unnorm)+PV via MFMA ---------
// Round-15 champion structure with ONE change: single-buffered Vt ->
// LDS 40960 B -> 3-4 blocks/CU (was 2 at 72KB; round-19 showed exact-fit
// LDS allocations fail, and blocks/CU is the only lever that moved PV).
// dv loaded in-PGEN (L2-hot 32KB) to keep VGPR ~110 (<128 = 16 waves/CU).
// Single-buffer race-safe: each wave's __syncthreads drains its own V DMA
// before the barrier publishes; V(it+1) issued after post-MFMA barrier,
// consumed after the NEXT pre-MFMA barrier (~500cy lead vs ~250cy L2).
__global__ __launch_bounds__(256) void k_attn_pv(const int* __restrict__ adj,
                                                 const short* __restrict__ WhbT,
                                                 const float* __restrict__ sv,
                                                 const float* __restrict__ dv,
                                                 float* __restrict__ accP,
                                                 float* __restrict__ zP,
                                                 int jspan) {
  __shared__ short Vt[256 * 64];   // 32 KB, [col][k] rows 128B, XOR-swizzled
  __shared__ short Pl[64 * 64];    // 8 KB, [row][k] rows 128B, XOR-swizzled
  const int t = threadIdx.x;
  const int rb = blockIdx.x * 64;
  const int pr = t >> 2;           // P-gen row
  const int pq = t & 3;            // P-gen 16-wide j-chunk
  const float s_i = sv[rb + pr];
  const int lane = t & 63;
  const int wid = t >> 6;
  const int l31 = lane & 31;
  const int lhi = lane >> 5;
  const int wrow = (wid >> 1) * 32;
  const int wcol = (wid & 1) * 128;
  char* PlB = (char*)Pl;
  const int arow = wrow + l31;
  const int abase = arow * 128 + lhi * 16;
  const int aswz = (arow & 7) << 4;
  const int pbyte = pr * 128 + pq * 32;
  const int pswz = (pr & 7) << 4;
  // V staging: instr r of wave w covers cols 64w+8r..+8; lane l -> col
  // 64w+8r+(l>>3), phys slot l&7; source chunk pre-swizzled (l&7)^((l>>3)&7).
  const int vcol0 = wid * 64 + (lane >> 3);
  const int vchunk = ((lane & 7) ^ ((lane >> 3) & 7)) * 8;
  const short* vsrc0 = WhbT + (size_t)vcol0 * NN + vchunk;
  short* vdst = Vt + wid * 4096;   // + r*512 shorts, wave-uniform

  f32x16 acc[4];
#pragma unroll
  for (int ct = 0; ct < 4; ++ct) acc[ct] = (f32x16)(0.f);
  float zacc = 0.f;

  const int j0 = blockIdx.y * jspan;
  const int iters = jspan >> 6;    // 32 at S=4; always even, >= 4

#define ISSUE_V(JB)                                                           \
  _Pragma("unroll")                                                           \
  for (int r = 0; r < 8; ++r)                                                 \
    gl2lds16(vsrc0 + (JB) + r * 8 * NN, vdst + r * 512);

#define LOAD_A(JB, AR)                                                        \
  {                                                                           \
    const int4* ap = (const int4*)(adj + (size_t)(rb + pr) * NN + (JB) + pq * 16); \
    _Pragma("unroll") for (int q = 0; q < 4; ++q) AR[q] = ap[q];              \
  }

#define PGEN_STORE(AR, JB)                                                    \
  {                                                                           \
    const float4* dp = (const float4*)(dv + (JB) + pq * 16);                  \
    alignas(16) short wb[16];                                                 \
    _Pragma("unroll")                                                         \
    for (int q = 0; q < 4; ++q) {                                             \
      float4 dq = dp[q];                                                      \
      float ev[4] = {dq.x, dq.y, dq.z, dq.w};                                 \
      int av[4] = {AR[q].x, AR[q].y, AR[q].z, AR[q].w};                       \
      _Pragma("unroll")                                                       \
      for (int u = 0; u < 4; ++u) {                                           \
        float e = s_i + ev[u];                                                \
        e = e >= 0.f ? e : 0.2f * e;                                          \
        float w = av[u] > 0 ? __expf(e) : 0.f;                                \
        short b = f2bf(w);                                                    \
        wb[q * 4 + u] = b;                                                    \
        zacc += bf2f(b);                                                      \
      }                                                                       \
    }                                                                         \
    *(float4*)(PlB + (pbyte ^ pswz)) = *(float4*)&wb[0];                      \
    *(float4*)(PlB + ((pbyte + 16) ^ pswz)) = *(float4*)&wb[8];               \
  }

#define MFMA_PHASE()                                                          \
  _Pragma("unroll")                                                           \
  for (int ks = 0; ks < 4; ++ks) {                                            \
    short8 af = *(const short8*)(PlB + ((abase + ks * 32) ^ aswz));           \
    _Pragma("unroll")                                                         \
    for (int ct = 0; ct < 4; ++ct) {                                          \
      const int c = wcol + ct * 32 + l31;                                     \
      short8 bf = *(const short8*)((char*)Vt +                                \
                    ((c * 128 + ks * 32 + lhi * 16) ^ ((c & 7) << 4)));       \
      acc[ct] = __builtin_amdgcn_mfma_f32_32x32x16_bf16(af, bf, acc[ct], 0, 0, 0); \
    }                                                                         \
  }

  // ---- prologue: adj for tiles 0,1 -> regs; V(0) in flight ----
  int4 aA[4], aB[4];
  LOAD_A(j0, aA);
  LOAD_A(j0 + 64, aB);
  ISSUE_V(j0);

  for (int it = 0; it < iters; it += 2) {
    const int jb = j0 + it * 64;
    // ---- even sub-iter: consume aA + Vt=V(it) ----
    PGEN_STORE(aA, jb);
    __syncthreads();                       // V(it) drained+published; Pl ready
    MFMA_PHASE();
    __syncthreads();                       // all waves done reading Vt
    ISSUE_V(jb + 64);                      // V(it+1) -> flies over next PGEN
    if (it + 2 < iters) LOAD_A(jb + 128, aA);        // adj(it+2), 2-deep
    // ---- odd sub-iter: consume aB + Vt=V(it+1) ----
    PGEN_STORE(aB, jb + 64);
    __syncthreads();
    MFMA_PHASE();
    __syncthreads();
    if (it + 2 < iters) {
      ISSUE_V(jb + 128);                   // V(it+2)
      LOAD_A(jb + 192, aB);                // adj(it+3)
    }
  }
#undef ISSUE_V
#undef LOAD_A
#undef PGEN_STORE
#undef MFMA_PHASE

  // ---- z: reduce 4 lanes (same row) via shfl ----
  float z2 = zacc + __shfl_xor(zacc, 1, 64);
  z2 += __shfl_xor(z2, 2, 64);
  if (pq == 0) zP[blockIdx.y * NN + rb + pr] = z2;
  // ---- acc epilogue ----
  const size_t slab = (size_t)blockIdx.y * NN * OUTF;
#pragma unroll
  for (int ct = 0; ct < 4; ++ct) {
#pragma unroll
    for (int q = 0; q < 16; ++q) {
      const int row = rb + wrow + 4 * lhi + (q & 3) + 8 * (q >> 2);
      const int col = wcol + ct * 32 + l31;
      accP[slab + (size_t)row * OUTF + col] = acc[ct][q];
    }
  }
}

// ---------------- Kernel 4: combine partials, normalize --------------------
__global__ __launch_bounds__(256) void k_reduce(const float* __restrict__ accP,
                                                const float* __restrict__ zP,
                                                float* __restrict__ out, int S) {
  const int row = blockIdx.x;
  const int f = threadIdx.x;
  const size_t idx = (size_t)row * OUTF + f;
  float a = 0.f, z = 0.f;
  for (int s = 0; s < S; ++s) {
    a += accP[(size_t)s * NN * OUTF + idx];
    z += zP[s * NN + row];
  }
  out[idx] = a / z;
}

extern "C" void kernel_launch(void* const* d_in, const int* in_sizes, int n_in,
                              void* d_out, int out_size, void* d_ws, size_t ws_size,
                              hipStream_t stream) {
  const float* h = (const float*)d_in[0];
  const int* adj = (const int*)d_in[1];
  const float* W = (const float*)d_in[2];
  const float* a_src = (const float*)d_in[3];
  const float* a_dst = (const float*)d_in[4];
  float* out = (float*)d_out;

  char* ws = (char*)d_ws;
  float* Wh = (float*)ws;                                    // 8 MB
  short* WhbT = (short*)(ws + (size_t)NN * OUTF * 4);        // 4 MB
  float* sv = (float*)(ws + (size_t)NN * OUTF * 6);          // 32 KB
  float* dvv = sv + NN;                                      // 32 KB
  float* zP = dvv + NN;                                      // 8*32 KB
  short* WThi = (short*)(zP + 8 * NN);                       // 256 KB
  short* WTlo = WThi + (size_t)OUTF * INF_;                  // 256 KB
  size_t off = (size_t)NN * OUTF * 6 + 2 * (size_t)NN * 4 + 8 * (size_t)NN * 4
             + 2 * (size_t)OUTF * INF_ * 2;
  off = (off + 255) & ~(size_t)255;
  const size_t slab_bytes = (size_t)NN * OUTF * 4;
  int S;
  float* accP;
  if (ws_size >= off + 4 * slab_bytes) { S = 4; accP = (float*)(ws + off); }
  else if (ws_size >= off + 2 * slab_bytes) { S = 2; accP = (float*)(ws + off); }
  else if (ws_size >= off + 1 * slab_bytes) { S = 1; accP = (float*)(ws + off); }
  else { S = 1; accP = out; }   // fallback: accumulate into out, normalize in place

  k_prepW<<<dim3(INF_ / 64, OUTF / 64), dim3(256), 0, stream>>>(W, WThi, WTlo);
  k_gemm_hW<<<dim3(NN / 64, OUTF / 64), dim3(256), 0, stream>>>(h, WThi, WTlo, Wh, WhbT);
  k_attn_sd<<<dim3(NN / 4), dim3(256), 0, stream>>>(Wh, a_src, a_dst, sv, dvv);
  k_attn_pv<<<dim3(NN / 64, S), dim3(256), 0, stream>>>(adj, WhbT, sv, dvv, accP, zP, NN / S);
  k_reduce<<<dim3(NN), dim3(256), 0, stream>>>(accP, zP, out, S);
}

// Round 21
// 148.067 us; speedup vs baseline: 2.4367x; 1.1397x over previous
//
#include <hip/hip_runtime.h>
#include <hip/hip_bf16.h>

#define NN 8192
#define INF_ 512
#define OUTF 256

typedef __attribute__((ext_vector_type(8))) short short8;
typedef __attribute__((ext_vector_type(16))) float f32x16;

static __device__ __forceinline__ short f2bf(float x) {
  unsigned u = __float_as_uint(x);
  unsigned r = (u + 0x7fff + ((u >> 16) & 1)) >> 16;   // RNE to bf16
  return (short)r;
}
static __device__ __forceinline__ float bf2f(short s) {
  return __uint_as_float(((unsigned)(unsigned short)s) << 16);
}
// async global->LDS, 16B per lane; LDS dest = wave-uniform base + lane*16
static __device__ __forceinline__ void gl2lds16(const short* g, short* l) {
  __builtin_amdgcn_global_load_lds(
      (const __attribute__((address_space(1))) unsigned int*)g,
      (__attribute__((address_space(3))) unsigned int*)l, 16, 0, 0);
}

// ---------------- Kernel 0: WT_hi/lo[col][k] = split-bf16(W[k][col]) -------
__global__ __launch_bounds__(256) void k_prepW(const float* __restrict__ W,
                                               short* __restrict__ WThi,
                                               short* __restrict__ WTlo) {
  __shared__ float tile[64][65];
  const int t = threadIdx.x;
  const int r0 = blockIdx.x * 64;   // k dim
  const int c0 = blockIdx.y * 64;   // col dim
  {
    const int ri = t >> 2, cq = t & 3;
    const float4* src = (const float4*)(W + (size_t)(r0 + ri) * OUTF + c0 + cq * 16);
#pragma unroll
    for (int q = 0; q < 4; ++q) {
      float4 v = src[q];
      int c = cq * 16 + q * 4;
      tile[ri][c + 0] = v.x; tile[ri][c + 1] = v.y;
      tile[ri][c + 2] = v.z; tile[ri][c + 3] = v.w;
    }
  }
  __syncthreads();
  {
    const int cj = t >> 2, rq = t & 3;
    alignas(16) short hi[16], lo[16];
#pragma unroll
    for (int q = 0; q < 16; ++q) {
      float x = tile[rq * 16 + q][cj];
      short hb = f2bf(x);
      hi[q] = hb;
      lo[q] = f2bf(x - bf2f(hb));
    }
    short* dh = WThi + (size_t)(c0 + cj) * INF_ + r0 + rq * 16;
    short* dl = WTlo + (size_t)(c0 + cj) * INF_ + r0 + rq * 16;
    *(float4*)dh = *(float4*)&hi[0];
    *(float4*)(dh + 8) = *(float4*)&hi[8];
    *(float4*)dl = *(float4*)&lo[0];
    *(float4*)(dl + 8) = *(float4*)&lo[8];
  }
}

// ---------------- Kernel 1: Wh = h @ W via split-bf16 MFMA -----------------
// (validated: 64x64 tile, grid (128,4) = 2 blocks/CU, B ping-pong)
__global__ __launch_bounds__(256, 2) void k_gemm_hW(const float* __restrict__ h,
                                                    const short* __restrict__ WThi,
                                                    const short* __restrict__ WTlo,
                                                    float* __restrict__ Wh,
                                                    short* __restrict__ WhbT) {
  __shared__ short Ahi[64 * 64];    // 8 KB, rows 128B, XOR-swizzled
  __shared__ short Alo[64 * 64];    // 8 KB
  __shared__ short Trans[64 * 72];  // 9 KB, [col][row] padded
  const int t = threadIdx.x;
  const int rb = blockIdx.x * 64;
  const int cb = blockIdx.y * 64;
  const int sr = t >> 2, sq = t & 3;        // h-stage: row, 16-k chunk
  const int lane = t & 63, wid = t >> 6;
  const int l31 = lane & 31, lhi = lane >> 5;
  const int wrow = (wid >> 1) * 32;         // 0/32
  const int wc = wid & 1;                   // 32-col half
  char* AhiB = (char*)Ahi;
  char* AloB = (char*)Alo;
  const int arow = wrow + l31;
  const int aswz = (arow & 7) << 4;
  const int sbyte = sr * 128 + sq * 32;
  const int sswz = (sr & 7) << 4;
  const size_t bcol = (size_t)(cb + wc * 32 + l31) * INF_ + lhi * 8;

  f32x16 acc = (f32x16)(0.f);

  float4 hreg[4];
  {
    const float4* hs = (const float4*)(h + (size_t)(rb + sr) * INF_ + sq * 16);
#pragma unroll
    for (int s = 0; s < 4; ++s) hreg[s] = hs[s];
  }
  short8 Bh[2][4], Bl[2][4];
#pragma unroll
  for (int k16 = 0; k16 < 4; ++k16) {
    Bh[0][k16] = *(const short8*)(WThi + bcol + k16 * 16);
    Bl[0][k16] = *(const short8*)(WTlo + bcol + k16 * 16);
  }

#pragma unroll
  for (int s8 = 0; s8 < 8; ++s8) {
    const int kb = s8 * 64;
    const int cur = s8 & 1, nxt = cur ^ 1;
    {
      alignas(16) short whi[16], wlo[16];
#pragma unroll
      for (int s = 0; s < 4; ++s) {
        float xs[4] = {hreg[s].x, hreg[s].y, hreg[s].z, hreg[s].w};
#pragma unroll
        for (int u = 0; u < 4; ++u) {
          short hb = f2bf(xs[u]);
          whi[s * 4 + u] = hb;
          wlo[s * 4 + u] = f2bf(xs[u] - bf2f(hb));
        }
      }
      *(float4*)(AhiB + (sbyte ^ sswz)) = *(float4*)&whi[0];
      *(float4*)(AhiB + ((sbyte + 16) ^ sswz)) = *(float4*)&whi[8];
      *(float4*)(AloB + (sbyte ^ sswz)) = *(float4*)&wlo[0];
      *(float4*)(AloB + ((sbyte + 16) ^ sswz)) = *(float4*)&wlo[8];
    }
    __syncthreads();
    if (s8 < 7) {
      const float4* hn = (const float4*)(h + (size_t)(rb + sr) * INF_ + kb + 64 + sq * 16);
#pragma unroll
      for (int s = 0; s < 4; ++s) hreg[s] = hn[s];
#pragma unroll
      for (int k16 = 0; k16 < 4; ++k16) {
        Bh[nxt][k16] = *(const short8*)(WThi + bcol + kb + 64 + k16 * 16);
        Bl[nxt][k16] = *(const short8*)(WTlo + bcol + kb + 64 + k16 * 16);
      }
    }
#pragma unroll
    for (int k16 = 0; k16 < 4; ++k16) {
      const int abyte = (arow * 128 + k16 * 32 + lhi * 16) ^ aswz;
      short8 ah = *(const short8*)(AhiB + abyte);
      short8 al = *(const short8*)(AloB + abyte);
      acc = __builtin_amdgcn_mfma_f32_32x32x16_bf16(ah, Bh[cur][k16], acc, 0, 0, 0);
      acc = __builtin_amdgcn_mfma_f32_32x32x16_bf16(ah, Bl[cur][k16], acc, 0, 0, 0);
      acc = __builtin_amdgcn_mfma_f32_32x32x16_bf16(al, Bh[cur][k16], acc, 0, 0, 0);
    }
    __syncthreads();
  }
#pragma unroll
  for (int q = 0; q < 16; ++q) {
    const int row = wrow + 4 * lhi + (q & 3) + 8 * (q >> 2);   // 0..63
    const int col = wc * 32 + l31;                             // 0..63
    Wh[(size_t)(rb + row) * OUTF + cb + col] = acc[q];
    Trans[col * 72 + row] = f2bf(acc[q]);
  }
  __syncthreads();
  {
    const int cj = t >> 2, rq = t & 3;   // col 0..63, row-quarter
    alignas(16) short tmp[16];
#pragma unroll
    for (int q = 0; q < 16; ++q) tmp[q] = Trans[cj * 72 + rq * 16 + q];
    short* dst = WhbT + (size_t)(cb + cj) * NN + rb + rq * 16;
    *(float4*)dst = *(float4*)&tmp[0];
    *(float4*)(dst + 8) = *(float4*)&tmp[8];
  }
}

// ---------------- Kernel 2: s/d per-row attention scalars ------------------
__global__ __launch_bounds__(256) void k_attn_sd(const float* __restrict__ Wh,
                                                 const float* __restrict__ a_src,
                                                 const float* __restrict__ a_dst,
                                                 float* __restrict__ sv,
                                                 float* __restrict__ dvv) {
  const int lane = threadIdx.x & 63;
  const int wave = threadIdx.x >> 6;
  const int row = blockIdx.x * 4 + wave;
  float4 wv = *reinterpret_cast<const float4*>(&Wh[(size_t)row * OUTF + lane * 4]);
  float4 as = *reinterpret_cast<const float4*>(&a_src[lane * 4]);
  float4 ad = *reinterpret_cast<const float4*>(&a_dst[lane * 4]);
  float ps = wv.x * as.x + wv.y * as.y + wv.z * as.z + wv.w * as.w;
  float pd = wv.x * ad.x + wv.y * ad.y + wv.z * ad.z + wv.w * ad.w;
#pragma unroll
  for (int off2 = 32; off2 > 0; off2 >>= 1) {
    ps += __shfl_down(ps, off2);
    pd += __shfl_down(pd, off2);
  }
  if (lane == 0) {
    sv[row] = ps;
    dvv[row] = pd;
  }
}

// ---------------- Kernel 3: fused mask+softmax(unnorm)+PV via MFMA ---------
// EXACT round-15 champion structure (measured best, 139.8 total): plain
// __syncthreads(), V via global_load_lds into double-buffered Vt
// (pre-swizzled source), single Pl, adj/dv reg-prefetched 2 tiles ahead.
// Only delta vs r15: LOAD_AD issued before ISSUE_V in the post-barrier slot
// (adj is the 900cy HBM load; earliest possible issue, same drain point).
// Five structural alternatives (counted-vmcnt, bit-pack, register-P,
// 128-row, single-buffer) all measured WORSE -- do not re-attempt blind.
__global__ __launch_bounds__(256) void k_attn_pv(const int* __restrict__ adj,
                                                 const short* __restrict__ WhbT,
                                                 const float* __restrict__ sv,
                                                 const float* __restrict__ dv,
                                                 float* __restrict__ accP,
                                                 float* __restrict__ zP,
                                                 int jspan) {
  __shared__ short Vt0[256 * 64];  // 32 KB, [col][k] rows 128B, XOR-swizzled
  __shared__ short Vt1[256 * 64];  // 32 KB
  __shared__ short Pl[64 * 64];    // 8 KB, [row][k] rows 128B, XOR-swizzled
  const int t = threadIdx.x;
  const int rb = blockIdx.x * 64;
  const int pr = t >> 2;           // P-gen row
  const int pq = t & 3;            // P-gen 16-wide j-chunk
  const float s_i = sv[rb + pr];
  const int lane = t & 63;
  const int wid = t >> 6;
  const int l31 = lane & 31;
  const int lhi = lane >> 5;
  const int wrow = (wid >> 1) * 32;
  const int wcol = (wid & 1) * 128;
  char* PlB = (char*)Pl;
  const int arow = wrow + l31;
  const int abase = arow * 128 + lhi * 16;
  const int aswz = (arow & 7) << 4;
  const int pbyte = pr * 128 + pq * 32;
  const int pswz = (pr & 7) << 4;
  // V staging: instr r of wave w covers cols 64w+8r..+8; lane l -> col
  // 64w+8r+(l>>3), phys slot l&7; source chunk pre-swizzled (l&7)^((l>>3)&7).
  const int vrow0 = wid * 64 + (lane >> 3);
  const int vchunk = ((lane & 7) ^ ((lane >> 3) & 7)) * 8;
  const short* vsrc0 = WhbT + (size_t)vrow0 * NN + vchunk;
  short* vdst0 = Vt0 + wid * 4096;   // + r*512 shorts, wave-uniform
  short* vdst1 = Vt1 + wid * 4096;

  f32x16 acc[4];
#pragma unroll
  for (int ct = 0; ct < 4; ++ct) acc[ct] = (f32x16)(0.f);
  float zacc = 0.f;

  const int j0 = blockIdx.y * jspan;
  const int iters = jspan >> 6;    // 32 at S=4; always even, >= 4

#define ISSUE_V(JB, VDST)                                                     \
  _Pragma("unroll")                                                           \
  for (int r = 0; r < 8; ++r)                                                 \
    gl2lds16(vsrc0 + (JB) + r * 8 * NN, (VDST) + r * 512);

#define LOAD_AD(JB, AR, DR)                                                   \
  {                                                                           \
    const int4* ap = (const int4*)(adj + (size_t)(rb + pr) * NN + (JB) + pq * 16); \
    _Pragma("unroll") for (int q = 0; q < 4; ++q) AR[q] = ap[q];              \
    const float4* dp = (const float4*)(dv + (JB) + pq * 16);                  \
    _Pragma("unroll") for (int q = 0; q < 4; ++q) DR[q] = dp[q];              \
  }

#define PGEN_STORE(AR, DR)                                                    \
  {                                                                           \
    alignas(16) short wb[16];                                                 \
    _Pragma("unroll")                                                         \
    for (int q = 0; q < 4; ++q) {                                             \
      float ev[4] = {DR[q].x, DR[q].y, DR[q].z, DR[q].w};                     \
      int av[4] = {AR[q].x, AR[q].y, AR[q].z, AR[q].w};                       \
      _Pragma("unroll")                                                       \
      for (int u = 0; u < 4; ++u) {                                           \
        float e = s_i + ev[u];                                                \
        e = e >= 0.f ? e : 0.2f * e;                                          \
        float w = av[u] > 0 ? __expf(e) : 0.f;                                \
        short b = f2bf(w);                                                    \
        wb[q * 4 + u] = b;                                                    \
        zacc += bf2f(b);                                                      \
      }                                                                       \
    }                                                                         \
    *(float4*)(PlB + (pbyte ^ pswz)) = *(float4*)&wb[0];                      \
    *(float4*)(PlB + ((pbyte + 16) ^ pswz)) = *(float4*)&wb[8];               \
  }

#define MFMA_PHASE(VTB)                                                       \
  _Pragma("unroll")                                                           \
  for (int ks = 0; ks < 4; ++ks) {                                            \
    short8 af = *(const short8*)(PlB + ((abase + ks * 32) ^ aswz));           \
    _Pragma("unroll")                                                         \
    for (int ct = 0; ct < 4; ++ct) {                                          \
      const int c = wcol + ct * 32 + l31;                                     \
      short8 bf = *(const short8*)((char*)(VTB) +                             \
                    ((c * 128 + ks * 32 + lhi * 16) ^ ((c & 7) << 4)));       \
      acc[ct] = __builtin_amdgcn_mfma_f32_32x32x16_bf16(af, bf, acc[ct], 0, 0, 0); \
    }                                                                         \
  }

  // ---- prologue: adj/dv for tiles 0,1 -> regs; V(0) -> Vt0 ----
  int4 aA[4], aB[4];
  float4 dA[4], dB[4];
  LOAD_AD(j0, aA, dA);
  LOAD_AD(j0 + 64, aB, dB);
  ISSUE_V(j0, vdst0);

  for (int it = 0; it < iters; it += 2) {
    const int jb = j0 + it * 64;
    // ---- even sub-iter: consume A + Vt0 ----
    PGEN_STORE(aA, dA);
    __syncthreads();                       // V(it) landed (drained here/prev)
    if (it + 2 < iters) LOAD_AD(jb + 128, aA, dA);   // adj(it+2) first (HBM)
    ISSUE_V(jb + 64, vdst1);               // V(it+1), flies across MFMA
    MFMA_PHASE(Vt0);
    __syncthreads();                       // drains vmcnt: V(it+1)/adj ready
    // ---- odd sub-iter: consume B + Vt1 ----
    PGEN_STORE(aB, dB);
    __syncthreads();
    if (it + 3 < iters) LOAD_AD(jb + 192, aB, dB);   // adj(it+3) first (HBM)
    if (it + 2 < iters) ISSUE_V(jb + 128, vdst0);    // V(it+2)
    MFMA_PHASE(Vt1);
    __syncthreads();
  }
#undef ISSUE_V
#undef LOAD_AD
#undef PGEN_STORE
#undef MFMA_PHASE

  // ---- z: reduce 4 lanes (same row) via shfl ----
  float z2 = zacc + __shfl_xor(zacc, 1, 64);
  z2 += __shfl_xor(z2, 2, 64);
  if (pq == 0) zP[blockIdx.y * NN + rb + pr] = z2;
  // ---- acc epilogue ----
  const size_t slab = (size_t)blockIdx.y * NN * OUTF;
#pragma unroll
  for (int ct = 0; ct < 4; ++ct) {
#pragma unroll
    for (int q = 0; q < 16; ++q) {
      const int row = rb + wrow + 4 * lhi + (q & 3) + 8 * (q >> 2);
      const int col = wcol + ct * 32 + l31;
      accP[slab + (size_t)row * OUTF + col] = acc[ct][q];
    }
  }
}

// ---------------- Kernel 4: combine partials, normalize (float4) -----------
__global__ __launch_bounds__(256) void k_reduce(const float* __restrict__ accP,
                                                const float* __restrict__ zP,
                                                float* __restrict__ out, int S) {
  const size_t tid = (size_t)blockIdx.x * 256 + threadIdx.x;  // float4 index
  const int row = (int)(tid >> 6);                            // 64 float4 per row
  float4 a = make_float4(0.f, 0.f, 0.f, 0.f);
  float z = 0.f;
  for (int s = 0; s < S; ++s) {
    float4 v = ((const float4*)(accP + (size_t)s * NN * OUTF))[tid];
    a.x += v.x; a.y += v.y; a.z += v.z; a.w += v.w;
    z += zP[s * NN + row];
  }
  float rz = 1.f / z;
  ((float4*)out)[tid] = make_float4(a.x * rz, a.y * rz, a.z * rz, a.w * rz);
}

extern "C" void kernel_launch(void* const* d_in, const int* in_sizes, int n_in,
                              void* d_out, int out_size, void* d_ws, size_t ws_size,
                              hipStream_t stream) {
  const float* h = (const float*)d_in[0];
  const int* adj = (const int*)d_in[1];
  const float* W = (const float*)d_in[2];
  const float* a_src = (const float*)d_in[3];
  const float* a_dst = (const float*)d_in[4];
  float* out = (float*)d_out;

  char* ws = (char*)d_ws;
  float* Wh = (float*)ws;                                    // 8 MB
  short* WhbT = (short*)(ws + (size_t)NN * OUTF * 4);        // 4 MB
  float* sv = (float*)(ws + (size_t)NN * OUTF * 6);          // 32 KB
  float* dvv = sv + NN;                                      // 32 KB
  float* zP = dvv + NN;                                      // 8*32 KB
  short* WThi = (short*)(zP + 8 * NN);                       // 256 KB
  short* WTlo = WThi + (size_t)OUTF * INF_;                  // 256 KB
  size_t off = (size_t)NN * OUTF * 6 + 2 * (size_t)NN * 4 + 8 * (size_t)NN * 4
             + 2 * (size_t)OUTF * INF_ * 2;
  off = (off + 255) & ~(size_t)255;
  const size_t slab_bytes = (size_t)NN * OUTF * 4;
  int S;
  float* accP;
  if (ws_size >= off + 4 * slab_bytes) { S = 4; accP = (float*)(ws + off); }
  else if (ws_size >= off + 2 * slab_bytes) { S = 2; accP = (float*)(ws + off); }
  else if (ws_size >= off + 1 * slab_bytes) { S = 1; accP = (float*)(ws + off); }
  else { S = 1; accP = out; }   // fallback: accumulate into out, normalize in place

  k_prepW<<<dim3(INF_ / 64, OUTF / 64), dim3(256), 0, stream>>>(W, WThi, WTlo);
  k_gemm_hW<<<dim3(NN / 64, OUTF / 64), dim3(256), 0, stream>>>(h, WThi, WTlo, Wh, WhbT);
  k_attn_sd<<<dim3(NN / 4), dim3(256), 0, stream>>>(Wh, a_src, a_dst, sv, dvv);
  k_attn_pv<<<dim3(NN / 64, S), dim3(256), 0, stream>>>(adj, WhbT, sv, dvv, accP, zP, NN / S);
  k_reduce<<<dim3(NN * OUTF / 1024), dim3(256), 0, stream>>>(accP, zP, out, S);
}

// Round 22
// 138.643 us; speedup vs baseline: 2.6023x; 1.0680x over previous
//
#include <hip/hip_runtime.h>
#include <hip/hip_bf16.h>

#define NN 8192
#define INF_ 512
#define OUTF 256

typedef __attribute__((ext_vector_type(8))) short short8;
typedef __attribute__((ext_vector_type(16))) float f32x16;

static __device__ __forceinline__ short f2bf(float x) {
  unsigned u = __float_as_uint(x);
  unsigned r = (u + 0x7fff + ((u >> 16) & 1)) >> 16;   // RNE to bf16
  return (short)r;
}
static __device__ __forceinline__ float bf2f(short s) {
  return __uint_as_float(((unsigned)(unsigned short)s) << 16);
}
// async global->LDS, 16B per lane; LDS dest = wave-uniform base + lane*16
static __device__ __forceinline__ void gl2lds16(const short* g, short* l) {
  __builtin_amdgcn_global_load_lds(
      (const __attribute__((address_space(1))) unsigned int*)g,
      (__attribute__((address_space(3))) unsigned int*)l, 16, 0, 0);
}

// ---------------- Kernel 0: WT_hi/lo[col][k] = split-bf16(W[k][col]) -------
__global__ __launch_bounds__(256) void k_prepW(const float* __restrict__ W,
                                               short* __restrict__ WThi,
                                               short* __restrict__ WTlo) {
  __shared__ float tile[64][65];
  const int t = threadIdx.x;
  const int r0 = blockIdx.x * 64;   // k dim
  const int c0 = blockIdx.y * 64;   // col dim
  {
    const int ri = t >> 2, cq = t & 3;
    const float4* src = (const float4*)(W + (size_t)(r0 + ri) * OUTF + c0 + cq * 16);
#pragma unroll
    for (int q = 0; q < 4; ++q) {
      float4 v = src[q];
      int c = cq * 16 + q * 4;
      tile[ri][c + 0] = v.x; tile[ri][c + 1] = v.y;
      tile[ri][c + 2] = v.z; tile[ri][c + 3] = v.w;
    }
  }
  __syncthreads();
  {
    const int cj = t >> 2, rq = t & 3;
    alignas(16) short hi[16], lo[16];
#pragma unroll
    for (int q = 0; q < 16; ++q) {
      float x = tile[rq * 16 + q][cj];
      short hb = f2bf(x);
      hi[q] = hb;
      lo[q] = f2bf(x - bf2f(hb));
    }
    short* dh = WThi + (size_t)(c0 + cj) * INF_ + r0 + rq * 16;
    short* dl = WTlo + (size_t)(c0 + cj) * INF_ + r0 + rq * 16;
    *(float4*)dh = *(float4*)&hi[0];
    *(float4*)(dh + 8) = *(float4*)&hi[8];
    *(float4*)dl = *(float4*)&lo[0];
    *(float4*)(dl + 8) = *(float4*)&lo[8];
  }
}

// ---------------- Kernel 1: Wh = h @ W via split-bf16 MFMA -----------------
// (validated: 64x64 tile, grid (128,4) = 2 blocks/CU, B ping-pong)
__global__ __launch_bounds__(256, 2) void k_gemm_hW(const float* __restrict__ h,
                                                    const short* __restrict__ WThi,
                                                    const short* __restrict__ WTlo,
                                                    float* __restrict__ Wh,
                                                    short* __restrict__ WhbT) {
  __shared__ short Ahi[64 * 64];    // 8 KB, rows 128B, XOR-swizzled
  __shared__ short Alo[64 * 64];    // 8 KB
  __shared__ short Trans[64 * 72];  // 9 KB, [col][row] padded
  const int t = threadIdx.x;
  const int rb = blockIdx.x * 64;
  const int cb = blockIdx.y * 64;
  const int sr = t >> 2, sq = t & 3;        // h-stage: row, 16-k chunk
  const int lane = t & 63, wid = t >> 6;
  const int l31 = lane & 31, lhi = lane >> 5;
  const int wrow = (wid >> 1) * 32;         // 0/32
  const int wc = wid & 1;                   // 32-col half
  char* AhiB = (char*)Ahi;
  char* AloB = (char*)Alo;
  const int arow = wrow + l31;
  const int aswz = (arow & 7) << 4;
  const int sbyte = sr * 128 + sq * 32;
  const int sswz = (sr & 7) << 4;
  const size_t bcol = (size_t)(cb + wc * 32 + l31) * INF_ + lhi * 8;

  f32x16 acc = (f32x16)(0.f);

  float4 hreg[4];
  {
    const float4* hs = (const float4*)(h + (size_t)(rb + sr) * INF_ + sq * 16);
#pragma unroll
    for (int s = 0; s < 4; ++s) hreg[s] = hs[s];
  }
  short8 Bh[2][4], Bl[2][4];
#pragma unroll
  for (int k16 = 0; k16 < 4; ++k16) {
    Bh[0][k16] = *(const short8*)(WThi + bcol + k16 * 16);
    Bl[0][k16] = *(const short8*)(WTlo + bcol + k16 * 16);
  }

#pragma unroll
  for (int s8 = 0; s8 < 8; ++s8) {
    const int kb = s8 * 64;
    const int cur = s8 & 1, nxt = cur ^ 1;
    {
      alignas(16) short whi[16], wlo[16];
#pragma unroll
      for (int s = 0; s < 4; ++s) {
        float xs[4] = {hreg[s].x, hreg[s].y, hreg[s].z, hreg[s].w};
#pragma unroll
        for (int u = 0; u < 4; ++u) {
          short hb = f2bf(xs[u]);
          whi[s * 4 + u] = hb;
          wlo[s * 4 + u] = f2bf(xs[u] - bf2f(hb));
        }
      }
      *(float4*)(AhiB + (sbyte ^ sswz)) = *(float4*)&whi[0];
      *(float4*)(AhiB + ((sbyte + 16) ^ sswz)) = *(float4*)&whi[8];
      *(float4*)(AloB + (sbyte ^ sswz)) = *(float4*)&wlo[0];
      *(float4*)(AloB + ((sbyte + 16) ^ sswz)) = *(float4*)&wlo[8];
    }
    __syncthreads();
    if (s8 < 7) {
      const float4* hn = (const float4*)(h + (size_t)(rb + sr) * INF_ + kb + 64 + sq * 16);
#pragma unroll
      for (int s = 0; s < 4; ++s) hreg[s] = hn[s];
#pragma unroll
      for (int k16 = 0; k16 < 4; ++k16) {
        Bh[nxt][k16] = *(const short8*)(WThi + bcol + kb + 64 + k16 * 16);
        Bl[nxt][k16] = *(const short8*)(WTlo + bcol + kb + 64 + k16 * 16);
      }
    }
#pragma unroll
    for (int k16 = 0; k16 < 4; ++k16) {
      const int abyte = (arow * 128 + k16 * 32 + lhi * 16) ^ aswz;
      short8 ah = *(const short8*)(AhiB + abyte);
      short8 al = *(const short8*)(AloB + abyte);
      acc = __builtin_amdgcn_mfma_f32_32x32x16_bf16(ah, Bh[cur][k16], acc, 0, 0, 0);
      acc = __builtin_amdgcn_mfma_f32_32x32x16_bf16(ah, Bl[cur][k16], acc, 0, 0, 0);
      acc = __builtin_amdgcn_mfma_f32_32x32x16_bf16(al, Bh[cur][k16], acc, 0, 0, 0);
    }
    __syncthreads();
  }
#pragma unroll
  for (int q = 0; q < 16; ++q) {
    const int row = wrow + 4 * lhi + (q & 3) + 8 * (q >> 2);   // 0..63
    const int col = wc * 32 + l31;                             // 0..63
    Wh[(size_t)(rb + row) * OUTF + cb + col] = acc[q];
    Trans[col * 72 + row] = f2bf(acc[q]);
  }
  __syncthreads();
  {
    const int cj = t >> 2, rq = t & 3;   // col 0..63, row-quarter
    alignas(16) short tmp[16];
#pragma unroll
    for (int q = 0; q < 16; ++q) tmp[q] = Trans[cj * 72 + rq * 16 + q];
    short* dst = WhbT + (size_t)(cb + cj) * NN + rb + rq * 16;
    *(float4*)dst = *(float4*)&tmp[0];
    *(float4*)(dst + 8) = *(float4*)&tmp[8];
  }
}

// ---------------- Kernel 2: s/d per-row attention scalars ------------------
__global__ __launch_bounds__(256) void k_attn_sd(const float* __restrict__ Wh,
                                                 const float* __restrict__ a_src,
                                                 const float* __restrict__ a_dst,
                                                 float* __restrict__ sv,
                                                 float* __restrict__ dvv) {
  const int lane = threadIdx.x & 63;
  const int wave = threadIdx.x >> 6;
  const int row = blockIdx.x * 4 + wave;
  float4 wv = *reinterpret_cast<const float4*>(&Wh[(size_t)row * OUTF + lane * 4]);
  float4 as = *reinterpret_cast<const float4*>(&a_src[lane * 4]);
  float4 ad = *reinterpret_cast<const float4*>(&a_dst[lane * 4]);
  float ps = wv.x * as.x + wv.y * as.y + wv.z * as.z + wv.w * as.w;
  float pd = wv.x * ad.x + wv.y * ad.y + wv.z * ad.z + wv.w * ad.w;
#pragma unroll
  for (int off2 = 32; off2 > 0; off2 >>= 1) {
    ps += __shfl_down(ps, off2);
    pd += __shfl_down(pd, off2);
  }
  if (lane == 0) {
    sv[row] = ps;
    dvv[row] = pd;
  }
}

// ---------------- Kernel 3: fused mask+softmax(unnorm)+PV via MFMA ---------
// EXACT round-15 champion (measured best, 139.8 total): plain __syncthreads,
// V via global_load_lds into double-buffered Vt (pre-swizzled source),
// single Pl, adj/dv reg-prefetched 2 tiles ahead, ISSUE_V FIRST after the
// barrier (r21 showed moving LOAD_AD first delays the V DMA and costs ~8us).
// Five structural alternatives all measured worse -- this order is pinned.
__global__ __launch_bounds__(256) void k_attn_pv(const int* __restrict__ adj,
                                                 const short* __restrict__ WhbT,
                                                 const float* __restrict__ sv,
                                                 const float* __restrict__ dv,
                                                 float* __restrict__ accP,
                                                 float* __restrict__ zP,
                                                 int jspan) {
  __shared__ short Vt0[256 * 64];  // 32 KB, [col][k] rows 128B, XOR-swizzled
  __shared__ short Vt1[256 * 64];  // 32 KB
  __shared__ short Pl[64 * 64];    // 8 KB, [row][k] rows 128B, XOR-swizzled
  const int t = threadIdx.x;
  const int rb = blockIdx.x * 64;
  const int pr = t >> 2;           // P-gen row
  const int pq = t & 3;            // P-gen 16-wide j-chunk
  const float s_i = sv[rb + pr];
  const int lane = t & 63;
  const int wid = t >> 6;
  const int l31 = lane & 31;
  const int lhi = lane >> 5;
  const int wrow = (wid >> 1) * 32;
  const int wcol = (wid & 1) * 128;
  char* PlB = (char*)Pl;
  const int arow = wrow + l31;
  const int abase = arow * 128 + lhi * 16;
  const int aswz = (arow & 7) << 4;
  const int pbyte = pr * 128 + pq * 32;
  const int pswz = (pr & 7) << 4;
  // V staging: instr r of wave w covers cols 64w+8r..+8; lane l -> col
  // 64w+8r+(l>>3), phys slot l&7; source chunk pre-swizzled (l&7)^((l>>3)&7).
  const int vrow0 = wid * 64 + (lane >> 3);
  const int vchunk = ((lane & 7) ^ ((lane >> 3) & 7)) * 8;
  const short* vsrc0 = WhbT + (size_t)vrow0 * NN + vchunk;
  short* vdst0 = Vt0 + wid * 4096;   // + r*512 shorts, wave-uniform
  short* vdst1 = Vt1 + wid * 4096;

  f32x16 acc[4];
#pragma unroll
  for (int ct = 0; ct < 4; ++ct) acc[ct] = (f32x16)(0.f);
  float zacc = 0.f;

  const int j0 = blockIdx.y * jspan;
  const int iters = jspan >> 6;    // 32 at S=4; always even, >= 4

#define ISSUE_V(JB, VDST)                                                     \
  _Pragma("unroll")                                                           \
  for (int r = 0; r < 8; ++r)                                                 \
    gl2lds16(vsrc0 + (JB) + r * 8 * NN, (VDST) + r * 512);

#define LOAD_AD(JB, AR, DR)                                                   \
  {                                                                           \
    const int4* ap = (const int4*)(adj + (size_t)(rb + pr) * NN + (JB) + pq * 16); \
    _Pragma("unroll") for (int q = 0; q < 4; ++q) AR[q] = ap[q];              \
    const float4* dp = (const float4*)(dv + (JB) + pq * 16);                  \
    _Pragma("unroll") for (int q = 0; q < 4; ++q) DR[q] = dp[q];              \
  }

#define PGEN_STORE(AR, DR)                                                    \
  {                                                                           \
    alignas(16) short wb[16];                                                 \
    _Pragma("unroll")                                                         \
    for (int q = 0; q < 4; ++q) {                                             \
      float ev[4] = {DR[q].x, DR[q].y, DR[q].z, DR[q].w};                     \
      int av[4] = {AR[q].x, AR[q].y, AR[q].z, AR[q].w};                       \
      _Pragma("unroll")                                                       \
      for (int u = 0; u < 4; ++u) {                                           \
        float e = s_i + ev[u];                                                \
        e = e >= 0.f ? e : 0.2f * e;                                          \
        float w = av[u] > 0 ? __expf(e) : 0.f;                                \
        short b = f2bf(w);                                                    \
        wb[q * 4 + u] = b;                                                    \
        zacc += bf2f(b);                                                      \
      }                                                                       \
    }                                                                         \
    *(float4*)(PlB + (pbyte ^ pswz)) = *(float4*)&wb[0];                      \
    *(float4*)(PlB + ((pbyte + 16) ^ pswz)) = *(float4*)&wb[8];               \
  }

#define MFMA_PHASE(VTB)                                                       \
  _Pragma("unroll")                                                           \
  for (int ks = 0; ks < 4; ++ks) {                                            \
    short8 af = *(const short8*)(PlB + ((abase + ks * 32) ^ aswz));           \
    _Pragma("unroll")                                                         \
    for (int ct = 0; ct < 4; ++ct) {                                          \
      const int c = wcol + ct * 32 + l31;                                     \
      short8 bf = *(const short8*)((char*)(VTB) +                             \
                    ((c * 128 + ks * 32 + lhi * 16) ^ ((c & 7) << 4)));       \
      acc[ct] = __builtin_amdgcn_mfma_f32_32x32x16_bf16(af, bf, acc[ct], 0, 0, 0); \
    }                                                                         \
  }

  // ---- prologue: adj/dv for tiles 0,1 -> regs; V(0) -> Vt0 ----
  int4 aA[4], aB[4];
  float4 dA[4], dB[4];
  LOAD_AD(j0, aA, dA);
  LOAD_AD(j0 + 64, aB, dB);
  ISSUE_V(j0, vdst0);

  for (int it = 0; it < iters; it += 2) {
    const int jb = j0 + it * 64;
    // ---- even sub-iter: consume A + Vt0 ----
    PGEN_STORE(aA, dA);
    __syncthreads();                       // V(it) landed (drained here/prev)
    ISSUE_V(jb + 64, vdst1);               // V(it+1) FIRST (barrier waits on it)
    if (it + 2 < iters) LOAD_AD(jb + 128, aA, dA);   // adj(it+2), 2-deep
    MFMA_PHASE(Vt0);
    __syncthreads();                       // drains vmcnt: V(it+1)/adj ready
    // ---- odd sub-iter: consume B + Vt1 ----
    PGEN_STORE(aB, dB);
    __syncthreads();
    if (it + 2 < iters) ISSUE_V(jb + 128, vdst0);    // V(it+2)
    if (it + 3 < iters) LOAD_AD(jb + 192, aB, dB);   // adj(it+3)
    MFMA_PHASE(Vt1);
    __syncthreads();
  }
#undef ISSUE_V
#undef LOAD_AD
#undef PGEN_STORE
#undef MFMA_PHASE

  // ---- z: reduce 4 lanes (same row) via shfl ----
  float z2 = zacc + __shfl_xor(zacc, 1, 64);
  z2 += __shfl_xor(z2, 2, 64);
  if (pq == 0) zP[blockIdx.y * NN + rb + pr] = z2;
  // ---- acc epilogue ----
  const size_t slab = (size_t)blockIdx.y * NN * OUTF;
#pragma unroll
  for (int ct = 0; ct < 4; ++ct) {
#pragma unroll
    for (int q = 0; q < 16; ++q) {
      const int row = rb + wrow + 4 * lhi + (q & 3) + 8 * (q >> 2);
      const int col = wcol + ct * 32 + l31;
      accP[slab + (size_t)row * OUTF + col] = acc[ct][q];
    }
  }
}

// ---------------- Kernel 4: combine partials, normalize (float4) -----------
__global__ __launch_bounds__(256) void k_reduce(const float* __restrict__ accP,
                                                const float* __restrict__ zP,
                                                float* __restrict__ out, int S) {
  const size_t tid = (size_t)blockIdx.x * 256 + threadIdx.x;  // float4 index
  const int row = (int)(tid >> 6);                            // 64 float4 per row
  float4 a = make_float4(0.f, 0.f, 0.f, 0.f);
  float z = 0.f;
  for (int s = 0; s < S; ++s) {
    float4 v = ((const float4*)(accP + (size_t)s * NN * OUTF))[tid];
    a.x += v.x; a.y += v.y; a.z += v.z; a.w += v.w;
    z += zP[s * NN + row];
  }
  float rz = 1.f / z;
  ((float4*)out)[tid] = make_float4(a.x * rz, a.y * rz, a.z * rz, a.w * rz);
}

extern "C" void kernel_launch(void* const* d_in, const int* in_sizes, int n_in,
                              void* d_out, int out_size, void* d_ws, size_t ws_size,
                              hipStream_t stream) {
  const float* h = (const float*)d_in[0];
  const int* adj = (const int*)d_in[1];
  const float* W = (const float*)d_in[2];
  const float* a_src = (const float*)d_in[3];
  const float* a_dst = (const float*)d_in[4];
  float* out = (float*)d_out;

  char* ws = (char*)d_ws;
  float* Wh = (float*)ws;                                    // 8 MB
  short* WhbT = (short*)(ws + (size_t)NN * OUTF * 4);        // 4 MB
  float* sv = (float*)(ws + (size_t)NN * OUTF * 6);          // 32 KB
  float* dvv = sv + NN;                                      // 32 KB
  float* zP = dvv + NN;                                      // 8*32 KB
  short* WThi = (short*)(zP + 8 * NN);                       // 256 KB
  short* WTlo = WThi + (size_t)OUTF * INF_;                  // 256 KB
  size_t off = (size_t)NN * OUTF * 6 + 2 * (size_t)NN * 4 + 8 * (size_t)NN * 4
             + 2 * (size_t)OUTF * INF_ * 2;
  off = (off + 255) & ~(size_t)255;
  const size_t slab_bytes = (size_t)NN * OUTF * 4;
  int S;
  float* accP;
  if (ws_size >= off + 4 * slab_bytes) { S = 4; accP = (float*)(ws + off); }
  else if (ws_size >= off + 2 * slab_bytes) { S = 2; accP = (float*)(ws + off); }
  else if (ws_size >= off + 1 * slab_bytes) { S = 1; accP = (float*)(ws + off); }
  else { S = 1; accP = out; }   // fallback: accumulate into out, normalize in place

  k_prepW<<<dim3(INF_ / 64, OUTF / 64), dim3(256), 0, stream>>>(W, WThi, WTlo);
  k_gemm_hW<<<dim3(NN / 64, OUTF / 64), dim3(256), 0, stream>>>(h, WThi, WTlo, Wh, WhbT);
  k_attn_sd<<<dim3(NN / 4), dim3(256), 0, stream>>>(Wh, a_src, a_dst, sv, dvv);
  k_attn_pv<<<dim3(NN / 64, S), dim3(256), 0, stream>>>(adj, WhbT, sv, dvv, accP, zP, NN / S);
  k_reduce<<<dim3(NN * OUTF / 1024), dim3(256), 0, stream>>>(accP, zP, out, S);
}

// Round 23
// 138.615 us; speedup vs baseline: 2.6029x; 1.0002x over previous
//
#include <hip/hip_runtime.h>
#include <hip/hip_bf16.h>

#define NN 8192
#define INF_ 512
#define OUTF 256

typedef __attribute__((ext_vector_type(8))) short short8;
typedef __attribute__((ext_vector_type(16))) float f32x16;

static __device__ __forceinline__ short f2bf(float x) {
  unsigned u = __float_as_uint(x);
  unsigned r = (u + 0x7fff + ((u >> 16) & 1)) >> 16;   // RNE to bf16
  return (short)r;
}
static __device__ __forceinline__ float bf2f(short s) {
  return __uint_as_float(((unsigned)(unsigned short)s) << 16);
}
// async global->LDS, 16B per lane; LDS dest = wave-uniform base + lane*16
static __device__ __forceinline__ void gl2lds16(const short* g, short* l) {
  __builtin_amdgcn_global_load_lds(
      (const __attribute__((address_space(1))) unsigned int*)g,
      (__attribute__((address_space(3))) unsigned int*)l, 16, 0, 0);
}

// ---------------- Kernel 0: WT_hi/lo[col][k] = split-bf16(W[k][col]) -------
__global__ __launch_bounds__(256) void k_prepW(const float* __restrict__ W,
                                               short* __restrict__ WThi,
                                               short* __restrict__ WTlo) {
  __shared__ float tile[64][65];
  const int t = threadIdx.x;
  const int r0 = blockIdx.x * 64;   // k dim
  const int c0 = blockIdx.y * 64;   // col dim
  {
    const int ri = t >> 2, cq = t & 3;
    const float4* src = (const float4*)(W + (size_t)(r0 + ri) * OUTF + c0 + cq * 16);
#pragma unroll
    for (int q = 0; q < 4; ++q) {
      float4 v = src[q];
      int c = cq * 16 + q * 4;
      tile[ri][c + 0] = v.x; tile[ri][c + 1] = v.y;
      tile[ri][c + 2] = v.z; tile[ri][c + 3] = v.w;
    }
  }
  __syncthreads();
  {
    const int cj = t >> 2, rq = t & 3;
    alignas(16) short hi[16], lo[16];
#pragma unroll
    for (int q = 0; q < 16; ++q) {
      float x = tile[rq * 16 + q][cj];
      short hb = f2bf(x);
      hi[q] = hb;
      lo[q] = f2bf(x - bf2f(hb));
    }
    short* dh = WThi + (size_t)(c0 + cj) * INF_ + r0 + rq * 16;
    short* dl = WTlo + (size_t)(c0 + cj) * INF_ + r0 + rq * 16;
    *(float4*)dh = *(float4*)&hi[0];
    *(float4*)(dh + 8) = *(float4*)&hi[8];
    *(float4*)dl = *(float4*)&lo[0];
    *(float4*)(dl + 8) = *(float4*)&lo[8];
  }
}

// ---------------- Kernel 1: Wh = h @ W via split-bf16 MFMA -----------------
// (validated: 64x64 tile, grid (128,4) = 2 blocks/CU, B ping-pong)
__global__ __launch_bounds__(256, 2) void k_gemm_hW(const float* __restrict__ h,
                                                    const short* __restrict__ WThi,
                                                    const short* __restrict__ WTlo,
                                                    float* __restrict__ Wh,
                                                    short* __restrict__ WhbT) {
  __shared__ short Ahi[64 * 64];    // 8 KB, rows 128B, XOR-swizzled
  __shared__ short Alo[64 * 64];    // 8 KB
  __shared__ short Trans[64 * 72];  // 9 KB, [col][row] padded
  const int t = threadIdx.x;
  const int rb = blockIdx.x * 64;
  const int cb = blockIdx.y * 64;
  const int sr = t >> 2, sq = t & 3;        // h-stage: row, 16-k chunk
  const int lane = t & 63, wid = t >> 6;
  const int l31 = lane & 31, lhi = lane >> 5;
  const int wrow = (wid >> 1) * 32;         // 0/32
  const int wc = wid & 1;                   // 32-col half
  char* AhiB = (char*)Ahi;
  char* AloB = (char*)Alo;
  const int arow = wrow + l31;
  const int aswz = (arow & 7) << 4;
  const int sbyte = sr * 128 + sq * 32;
  const int sswz = (sr & 7) << 4;
  const size_t bcol = (size_t)(cb + wc * 32 + l31) * INF_ + lhi * 8;

  f32x16 acc = (f32x16)(0.f);

  float4 hreg[4];
  {
    const float4* hs = (const float4*)(h + (size_t)(rb + sr) * INF_ + sq * 16);
#pragma unroll
    for (int s = 0; s < 4; ++s) hreg[s] = hs[s];
  }
  short8 Bh[2][4], Bl[2][4];
#pragma unroll
  for (int k16 = 0; k16 < 4; ++k16) {
    Bh[0][k16] = *(const short8*)(WThi + bcol + k16 * 16);
    Bl[0][k16] = *(const short8*)(WTlo + bcol + k16 * 16);
  }

#pragma unroll
  for (int s8 = 0; s8 < 8; ++s8) {
    const int kb = s8 * 64;
    const int cur = s8 & 1, nxt = cur ^ 1;
    {
      alignas(16) short whi[16], wlo[16];
#pragma unroll
      for (int s = 0; s < 4; ++s) {
        float xs[4] = {hreg[s].x, hreg[s].y, hreg[s].z, hreg[s].w};
#pragma unroll
        for (int u = 0; u < 4; ++u) {
          short hb = f2bf(xs[u]);
          whi[s * 4 + u] = hb;
          wlo[s * 4 + u] = f2bf(xs[u] - bf2f(hb));
        }
      }
      *(float4*)(AhiB + (sbyte ^ sswz)) = *(float4*)&whi[0];
      *(float4*)(AhiB + ((sbyte + 16) ^ sswz)) = *(float4*)&whi[8];
      *(float4*)(AloB + (sbyte ^ sswz)) = *(float4*)&wlo[0];
      *(float4*)(AloB + ((sbyte + 16) ^ sswz)) = *(float4*)&wlo[8];
    }
    __syncthreads();
    if (s8 < 7) {
      const float4* hn = (const float4*)(h + (size_t)(rb + sr) * INF_ + kb + 64 + sq * 16);
#pragma unroll
      for (int s = 0; s < 4; ++s) hreg[s] = hn[s];
#pragma unroll
      for (int k16 = 0; k16 < 4; ++k16) {
        Bh[nxt][k16] = *(const short8*)(WThi + bcol + kb + 64 + k16 * 16);
        Bl[nxt][k16] = *(const short8*)(WTlo + bcol + kb + 64 + k16 * 16);
      }
    }
#pragma unroll
    for (int k16 = 0; k16 < 4; ++k16) {
      const int abyte = (arow * 128 + k16 * 32 + lhi * 16) ^ aswz;
      short8 ah = *(const short8*)(AhiB + abyte);
      short8 al = *(const short8*)(AloB + abyte);
      acc = __builtin_amdgcn_mfma_f32_32x32x16_bf16(ah, Bh[cur][k16], acc, 0, 0, 0);
      acc = __builtin_amdgcn_mfma_f32_32x32x16_bf16(ah, Bl[cur][k16], acc, 0, 0, 0);
      acc = __builtin_amdgcn_mfma_f32_32x32x16_bf16(al, Bh[cur][k16], acc, 0, 0, 0);
    }
    __syncthreads();
  }
#pragma unroll
  for (int q = 0; q < 16; ++q) {
    const int row = wrow + 4 * lhi + (q & 3) + 8 * (q >> 2);   // 0..63
    const int col = wc * 32 + l31;                             // 0..63
    Wh[(size_t)(rb + row) * OUTF + cb + col] = acc[q];
    Trans[col * 72 + row] = f2bf(acc[q]);
  }
  __syncthreads();
  {
    const int cj = t >> 2, rq = t & 3;   // col 0..63, row-quarter
    alignas(16) short tmp[16];
#pragma unroll
    for (int q = 0; q < 16; ++q) tmp[q] = Trans[cj * 72 + rq * 16 + q];
    short* dst = WhbT + (size_t)(cb + cj) * NN + rb + rq * 16;
    *(float4*)dst = *(float4*)&tmp[0];
    *(float4*)(dst + 8) = *(float4*)&tmp[8];
  }
}

// ---------------- Kernel 2: s/d per-row attention scalars ------------------
__global__ __launch_bounds__(256) void k_attn_sd(const float* __restrict__ Wh,
                                                 const float* __restrict__ a_src,
                                                 const float* __restrict__ a_dst,
                                                 float* __restrict__ sv,
                                                 float* __restrict__ dvv) {
  const int lane = threadIdx.x & 63;
  const int wave = threadIdx.x >> 6;
  const int row = blockIdx.x * 4 + wave;
  float4 wv = *reinterpret_cast<const float4*>(&Wh[(size_t)row * OUTF + lane * 4]);
  float4 as = *reinterpret_cast<const float4*>(&a_src[lane * 4]);
  float4 ad = *reinterpret_cast<const float4*>(&a_dst[lane * 4]);
  float ps = wv.x * as.x + wv.y * as.y + wv.z * as.z + wv.w * as.w;
  float pd = wv.x * ad.x + wv.y * ad.y + wv.z * ad.z + wv.w * ad.w;
#pragma unroll
  for (int off2 = 32; off2 > 0; off2 >>= 1) {
    ps += __shfl_down(ps, off2);
    pd += __shfl_down(pd, off2);
  }
  if (lane == 0) {
    sv[row] = ps;
    dvv[row] = pd;
  }
}

// ---------------- Kernel 3: fused mask+softmax(unnorm)+PV via MFMA ---------
// Champion structure (138.6 total) with ONE change: PGEN uses
// v_cvt_pk_bf16_f32 (1 op / 2 elts, validated absmax 3.9e-3 in round 13)
// + fmax-lrelu + fp32 zacc, cutting ~60 VALU ops/thread/sub-iter from the
// serial {PGEN -> barrier -> MFMA} chain. No sched_barrier (r13's poison).
// Order pinned: ISSUE_V FIRST after barrier (r21: swapping costs ~8us).
__global__ __launch_bounds__(256) void k_attn_pv(const int* __restrict__ adj,
                                                 const short* __restrict__ WhbT,
                                                 const float* __restrict__ sv,
                                                 const float* __restrict__ dv,
                                                 float* __restrict__ accP,
                                                 float* __restrict__ zP,
                                                 int jspan) {
  __shared__ short Vt0[256 * 64];  // 32 KB, [col][k] rows 128B, XOR-swizzled
  __shared__ short Vt1[256 * 64];  // 32 KB
  __shared__ short Pl[64 * 64];    // 8 KB, [row][k] rows 128B, XOR-swizzled
  const int t = threadIdx.x;
  const int rb = blockIdx.x * 64;
  const int pr = t >> 2;           // P-gen row
  const int pq = t & 3;            // P-gen 16-wide j-chunk
  const float s_i = sv[rb + pr];
  const int lane = t & 63;
  const int wid = t >> 6;
  const int l31 = lane & 31;
  const int lhi = lane >> 5;
  const int wrow = (wid >> 1) * 32;
  const int wcol = (wid & 1) * 128;
  char* PlB = (char*)Pl;
  const int arow = wrow + l31;
  const int abase = arow * 128 + lhi * 16;
  const int aswz = (arow & 7) << 4;
  const int pbyte = pr * 128 + pq * 32;
  const int pswz = (pr & 7) << 4;
  // V staging: instr r of wave w covers cols 64w+8r..+8; lane l -> col
  // 64w+8r+(l>>3), phys slot l&7; source chunk pre-swizzled (l&7)^((l>>3)&7).
  const int vrow0 = wid * 64 + (lane >> 3);
  const int vchunk = ((lane & 7) ^ ((lane >> 3) & 7)) * 8;
  const short* vsrc0 = WhbT + (size_t)vrow0 * NN + vchunk;
  short* vdst0 = Vt0 + wid * 4096;   // + r*512 shorts, wave-uniform
  short* vdst1 = Vt1 + wid * 4096;

  f32x16 acc[4];
#pragma unroll
  for (int ct = 0; ct < 4; ++ct) acc[ct] = (f32x16)(0.f);
  float zacc = 0.f;

  const int j0 = blockIdx.y * jspan;
  const int iters = jspan >> 6;    // 32 at S=4; always even, >= 4

#define ISSUE_V(JB, VDST)                                                     \
  _Pragma("unroll")                                                           \
  for (int r = 0; r < 8; ++r)                                                 \
    gl2lds16(vsrc0 + (JB) + r * 8 * NN, (VDST) + r * 512);

#define LOAD_AD(JB, AR, DR)                                                   \
  {                                                                           \
    const int4* ap = (const int4*)(adj + (size_t)(rb + pr) * NN + (JB) + pq * 16); \
    _Pragma("unroll") for (int q = 0; q < 4; ++q) AR[q] = ap[q];              \
    const float4* dp = (const float4*)(dv + (JB) + pq * 16);                  \
    _Pragma("unroll") for (int q = 0; q < 4; ++q) DR[q] = dp[q];              \
  }

#define PGEN_STORE(AR, DR)                                                    \
  {                                                                           \
    float wv[16];                                                             \
    _Pragma("unroll")                                                         \
    for (int q = 0; q < 4; ++q) {                                             \
      float ev[4] = {DR[q].x, DR[q].y, DR[q].z, DR[q].w};                     \
      int av[4] = {AR[q].x, AR[q].y, AR[q].z, AR[q].w};                       \
      _Pragma("unroll")                                                       \
      for (int u = 0; u < 4; ++u) {                                           \
        float e = s_i + ev[u];                                                \
        e = fmaxf(e, 0.2f * e);                                               \
        float w = av[u] > 0 ? __expf(e) : 0.f;                                \
        wv[q * 4 + u] = w;                                                    \
        zacc += w;                                                            \
      }                                                                       \
    }                                                                         \
    alignas(16) unsigned pk[8];                                               \
    _Pragma("unroll")                                                         \
    for (int i2 = 0; i2 < 8; ++i2)                                            \
      asm("v_cvt_pk_bf16_f32 %0, %1, %2"                                      \
          : "=v"(pk[i2]) : "v"(wv[2 * i2]), "v"(wv[2 * i2 + 1]));             \
    *(float4*)(PlB + (pbyte ^ pswz)) = *(float4*)&pk[0];                      \
    *(float4*)(PlB + ((pbyte + 16) ^ pswz)) = *(float4*)&pk[4];               \
  }

#define MFMA_PHASE(VTB)                                                       \
  _Pragma("unroll")                                                           \
  for (int ks = 0; ks < 4; ++ks) {                                            \
    short8 af = *(const short8*)(PlB + ((abase + ks * 32) ^ aswz));           \
    _Pragma("unroll")                                                         \
    for (int ct = 0; ct < 4; ++ct) {                                          \
      const int c = wcol + ct * 32 + l31;                                     \
      short8 bf = *(const short8*)((char*)(VTB) +                             \
                    ((c * 128 + ks * 32 + lhi * 16) ^ ((c & 7) << 4)));       \
      acc[ct] = __builtin_amdgcn_mfma_f32_32x32x16_bf16(af, bf, acc[ct], 0, 0, 0); \
    }                                                                         \
  }

  // ---- prologue: adj/dv for tiles 0,1 -> regs; V(0) -> Vt0 ----
  int4 aA[4], aB[4];
  float4 dA[4], dB[4];
  LOAD_AD(j0, aA, dA);
  LOAD_AD(j0 + 64, aB, dB);
  ISSUE_V(j0, vdst0);

  for (int it = 0; it < iters; it += 2) {
    const int jb = j0 + it * 64;
    // ---- even sub-iter: consume A + Vt0 ----
    PGEN_STORE(aA, dA);
    __syncthreads();                       // V(it) landed (drained here/prev)
    ISSUE_V(jb + 64, vdst1);               // V(it+1) FIRST (barrier waits on it)
    if (it + 2 < iters) LOAD_AD(jb + 128, aA, dA);   // adj(it+2), 2-deep
    MFMA_PHASE(Vt0);
    __syncthreads();                       // drains vmcnt: V(it+1)/adj ready
    // ---- odd sub-iter: consume B + Vt1 ----
    PGEN_STORE(aB, dB);
    __syncthreads();
    if (it + 2 < iters) ISSUE_V(jb + 128, vdst0);    // V(it+2)
    if (it + 3 < iters) LOAD_AD(jb + 192, aB, dB);   // adj(it+3)
    MFMA_PHASE(Vt1);
    __syncthreads();
  }
#undef ISSUE_V
#undef LOAD_AD
#undef PGEN_STORE
#undef MFMA_PHASE

  // ---- z: reduce 4 lanes (same row) via shfl ----
  float z2 = zacc + __shfl_xor(zacc, 1, 64);
  z2 += __shfl_xor(z2, 2, 64);
  if (pq == 0) zP[blockIdx.y * NN + rb + pr] = z2;
  // ---- acc epilogue ----
  const size_t slab = (size_t)blockIdx.y * NN * OUTF;
#pragma unroll
  for (int ct = 0; ct < 4; ++ct) {
#pragma unroll
    for (int q = 0; q < 16; ++q) {
      const int row = rb + wrow + 4 * lhi + (q & 3) + 8 * (q >> 2);
      const int col = wcol + ct * 32 + l31;
      accP[slab + (size_t)row * OUTF + col] = acc[ct][q];
    }
  }
}

// ---------------- Kernel 4: combine partials, normalize (float4) -----------
__global__ __launch_bounds__(256) void k_reduce(const float* __restrict__ accP,
                                                const float* __restrict__ zP,
                                                float* __restrict__ out, int S) {
  const size_t tid = (size_t)blockIdx.x * 256 + threadIdx.x;  // float4 index
  const int row = (int)(tid >> 6);                            // 64 float4 per row
  float4 a = make_float4(0.f, 0.f, 0.f, 0.f);
  float z = 0.f;
  for (int s = 0; s < S; ++s) {
    float4 v = ((const float4*)(accP + (size_t)s * NN * OUTF))[tid];
    a.x += v.x; a.y += v.y; a.z += v.z; a.w += v.w;
    z += zP[s * NN + row];
  }
  float rz = 1.f / z;
  ((float4*)out)[tid] = make_float4(a.x * rz, a.y * rz, a.z * rz, a.w * rz);
}

extern "C" void kernel_launch(void* const* d_in, const int* in_sizes, int n_in,
                              void* d_out, int out_size, void* d_ws, size_t ws_size,
                              hipStream_t stream) {
  const float* h = (const float*)d_in[0];
  const int* adj = (const int*)d_in[1];
  const float* W = (const float*)d_in[2];
  const float* a_src = (const float*)d_in[3];
  const float* a_dst = (const float*)d_in[4];
  float* out = (float*)d_out;

  char* ws = (char*)d_ws;
  float* Wh = (float*)ws;                                    // 8 MB
  short* WhbT = (short*)(ws + (size_t)NN * OUTF * 4);        // 4 MB
  float* sv = (float*)(ws + (size_t)NN * OUTF * 6);          // 32 KB
  float* dvv = sv + NN;                                      // 32 KB
  float* zP = dvv + NN;                                      // 8*32 KB
  short* WThi = (short*)(zP + 8 * NN);                       // 256 KB
  short* WTlo = WThi + (size_t)OUTF * INF_;                  // 256 KB
  size_t off = (size_t)NN * OUTF * 6 + 2 * (size_t)NN * 4 + 8 * (size_t)NN * 4
             + 2 * (size_t)OUTF * INF_ * 2;
  off = (off + 255) & ~(size_t)255;
  const size_t slab_bytes = (size_t)NN * OUTF * 4;
  int S;
  float* accP;
  if (ws_size >= off + 4 * slab_bytes) { S = 4; accP = (float*)(ws + off); }
  else if (ws_size >= off + 2 * slab_bytes) { S = 2; accP = (float*)(ws + off); }
  else if (ws_size >= off + 1 * slab_bytes) { S = 1; accP = (float*)(ws + off); }
  else { S = 1; accP = out; }   // fallback: accumulate into out, normalize in place

  k_prepW<<<dim3(INF_ / 64, OUTF / 64), dim3(256), 0, stream>>>(W, WThi, WTlo);
  k_gemm_hW<<<dim3(NN / 64, OUTF / 64), dim3(256), 0, stream>>>(h, WThi, WTlo, Wh, WhbT);
  k_attn_sd<<<dim3(NN / 4), dim3(256), 0, stream>>>(Wh, a_src, a_dst, sv, dvv);
  k_attn_pv<<<dim3(NN / 64, S), dim3(256), 0, stream>>>(adj, WhbT, sv, dvv, accP, zP, NN / S);
  k_reduce<<<dim3(NN * OUTF / 1024), dim3(256), 0, stream>>>(accP, zP, out, S);
}